// Round 3
// baseline (1532.022 us; speedup 1.0000x reference)
//
#include <hip/hip_runtime.h>
#include <cstdint>
#include <cstddef>

// ---------- bf16 helpers (OCP bf16 = upper 16 bits of f32) ----------
__device__ __forceinline__ float bf2f(unsigned short u) {
  return __uint_as_float(((unsigned)u) << 16);
}
__device__ __forceinline__ unsigned short f2bf(float f) {
  unsigned u = __float_as_uint(f);
  u = (u + 0x7FFFu + ((u >> 16) & 1u)) >> 16;  // RNE
  return (unsigned short)u;
}

// ---------- edge_index layout probe ----------
// int64 layout: odd int32 words are high halves of node ids -> all 0.
// int32 layout: odd words are real node ids -> some nonzero (w.p. ~1).
__global__ void detect_kernel(const int* __restrict__ ei, int* __restrict__ flag) {
  int any = 0;
  for (int j = threadIdx.x; j < 4096; j += 256) any |= (ei[2 * j + 1] != 0);
  if (any) atomicOr(flag, 1);  // 1 => int32 layout
}

__device__ __forceinline__ int edge_src(const int* ei, int f, int e, int i) {
  return f ? ei[i] : ei[2 * (size_t)i];
}
__device__ __forceinline__ int edge_dst(const int* ei, int f, int e, int i) {
  return f ? ei[(size_t)e + i] : ei[2 * (size_t)e + 2 * (size_t)i];
}

// ---------- CSR build ----------
__global__ void hist_kernel(const int* __restrict__ ei, const int* __restrict__ flag,
                            int* __restrict__ cnt, int e) {
  int i = blockIdx.x * blockDim.x + threadIdx.x;
  if (i < e) atomicAdd(&cnt[edge_dst(ei, *flag, e, i)], 1);
}

// single-block exclusive scan (n ~ 1e5, chunks of 1024)
__global__ void scan_kernel(const int* __restrict__ cnt, int* __restrict__ rp, int n) {
  __shared__ int lds[1024];
  __shared__ int carry;
  const int tid = threadIdx.x;
  if (tid == 0) carry = 0;
  __syncthreads();
  for (int base = 0; base < n; base += 1024) {
    int idx = base + tid;
    int v = (idx < n) ? cnt[idx] : 0;
    lds[tid] = v;
    __syncthreads();
    for (int off = 1; off < 1024; off <<= 1) {
      int t = (tid >= off) ? lds[tid - off] : 0;
      __syncthreads();
      lds[tid] += t;
      __syncthreads();
    }
    if (idx < n) rp[idx] = carry + lds[tid] - v;  // exclusive
    int tot = lds[1023];
    __syncthreads();
    if (tid == 0) carry += tot;
    __syncthreads();
  }
  if (tid == 0) rp[n] = carry;
}

__global__ void initcur_kernel(const int* __restrict__ rp, int* __restrict__ cur, int n) {
  int i = blockIdx.x * blockDim.x + threadIdx.x;
  if (i < n) cur[i] = rp[i];
}

__global__ void fill_kernel(const int* __restrict__ ei, const int* __restrict__ flag,
                            int* __restrict__ cur, int* __restrict__ col, int e) {
  int i = blockIdx.x * blockDim.x + threadIdx.x;
  if (i < e) {
    int f = *flag;
    int s = edge_src(ei, f, e, i);
    int d = edge_dst(ei, f, e, i);
    int p = atomicAdd(&cur[d], 1);
    col[p] = s;
  }
}

// ---------- GEMM: Y[n,C] = X[n,128] @ W[128,C] (+bias), f32 in; Y f32 or bf16 ----------
template <int C, bool YBF>
__launch_bounds__(256)
__global__ void gemm_k128(const float* Xv, const float* __restrict__ Wf,
                          const float* __restrict__ biasf, void* Yv, int n) {
  constexpr int TC = C / 32;               // 4 (C=128) or 2 (C=64)
  __shared__ float xs[64 * 32];            // 8 KB
  __shared__ float wsm[32 * C];            // 16 KB / 8 KB
  const int t = threadIdx.x;
  const int tc = t & 31;
  const int trg = t >> 5;
  const int row0 = blockIdx.x * 64;

  float acc[8][TC];
#pragma unroll
  for (int i = 0; i < 8; ++i)
#pragma unroll
    for (int c = 0; c < TC; ++c) acc[i][c] = 0.f;

  for (int kc = 0; kc < 128; kc += 32) {
    {  // stage X tile: 64 rows x 32 k
      const int r = t >> 2;
      const int j = (t & 3) * 8;
      const int row = row0 + r;
      float v[8];
      if (row < n) {
        const float* xp = Xv + (size_t)row * 128 + kc + j;
        float4 a = *(const float4*)xp;
        float4 b = *(const float4*)(xp + 4);
        v[0] = a.x; v[1] = a.y; v[2] = a.z; v[3] = a.w;
        v[4] = b.x; v[5] = b.y; v[6] = b.z; v[7] = b.w;
      } else {
#pragma unroll
        for (int q = 0; q < 8; ++q) v[q] = 0.f;
      }
      *(float4*)&xs[r * 32 + j]     = make_float4(v[0], v[1], v[2], v[3]);
      *(float4*)&xs[r * 32 + j + 4] = make_float4(v[4], v[5], v[6], v[7]);
    }
    {  // stage W tile: 32 x C
      constexpr int per = (32 * C) / 256;  // 16 or 8 floats/thread
      const float* wp = Wf + (size_t)kc * C + t * per;
      float* wl = wsm + t * per;
#pragma unroll
      for (int q = 0; q < per; q += 4) *(float4*)(wl + q) = *(const float4*)(wp + q);
    }
    __syncthreads();
#pragma unroll
    for (int k = 0; k < 32; k += 4) {
      float wv[4][TC];
#pragma unroll
      for (int k2 = 0; k2 < 4; ++k2) {
        if constexpr (TC == 4) {
          float4 w4 = *(const float4*)&wsm[(k + k2) * C + tc * 4];
          wv[k2][0] = w4.x; wv[k2][1] = w4.y; wv[k2][2] = w4.z; wv[k2][3] = w4.w;
        } else {
          float2 w2 = *(const float2*)&wsm[(k + k2) * C + tc * 2];
          wv[k2][0] = w2.x; wv[k2][1] = w2.y;
        }
      }
#pragma unroll
      for (int i = 0; i < 8; ++i) {
        float4 x4 = *(const float4*)&xs[(trg * 8 + i) * 32 + k];
        float xa[4] = {x4.x, x4.y, x4.z, x4.w};
#pragma unroll
        for (int k2 = 0; k2 < 4; ++k2)
#pragma unroll
          for (int c = 0; c < TC; ++c)
            acc[i][c] = fmaf(xa[k2], wv[k2][c], acc[i][c]);
      }
    }
    __syncthreads();
  }
  // epilogue
  float bv[TC];
#pragma unroll
  for (int c = 0; c < TC; ++c) bv[c] = biasf ? biasf[tc * TC + c] : 0.f;
#pragma unroll
  for (int i = 0; i < 8; ++i) {
    const int row = row0 + trg * 8 + i;
    if (row < n) {
      float r[TC];
#pragma unroll
      for (int c = 0; c < TC; ++c) r[c] = acc[i][c] + bv[c];
      if constexpr (YBF) {
        unsigned short* yp = (unsigned short*)Yv + (size_t)row * C + tc * TC;
        if constexpr (TC == 4) {
          uint2 u;
          u.x = (unsigned)f2bf(r[0]) | ((unsigned)f2bf(r[1]) << 16);
          u.y = (unsigned)f2bf(r[2]) | ((unsigned)f2bf(r[3]) << 16);
          *(uint2*)yp = u;
        } else {
          *(unsigned*)yp = (unsigned)f2bf(r[0]) | ((unsigned)f2bf(r[1]) << 16);
        }
      } else {
        float* yp = (float*)Yv + (size_t)row * C + tc * TC;
        if constexpr (TC == 4) *(float4*)yp = make_float4(r[0], r[1], r[2], r[3]);
        else                   *(float2*)yp = make_float2(r[0], r[1]);
      }
    }
  }
}

// ---------- per-node attention logits from bf16 hg ----------
template <int C>
__launch_bounds__(256)
__global__ void attn_logits(const unsigned short* __restrict__ hg,
                            const float* __restrict__ asrc, const float* __restrict__ adst,
                            float* __restrict__ als, float* __restrict__ ald, int n) {
  const int node = blockIdx.x * 4 + (threadIdx.x >> 6);
  if (node >= n) return;
  const int lane = threadIdx.x & 63;
  float s, d;
  if constexpr (C == 128) {
    unsigned raw = *(const unsigned*)(hg + (size_t)node * 128 + 2 * lane);
    float h0 = __uint_as_float(raw << 16);
    float h1 = __uint_as_float(raw & 0xFFFF0000u);
    float2 av = *(const float2*)(asrc + 2 * lane);
    float2 dv = *(const float2*)(adst + 2 * lane);
    s = h0 * av.x + h1 * av.y;
    d = h0 * dv.x + h1 * dv.y;
  } else {
    float h0 = bf2f(hg[(size_t)node * C + lane]);
    s = h0 * asrc[lane];
    d = h0 * adst[lane];
  }
  for (int o = 32; o > 0; o >>= 1) {
    s += __shfl_xor(s, o, 64);
    d += __shfl_xor(d, o, 64);
  }
  if (lane == 0) { als[node] = s; ald[node] = d; }
}

// ---------- aggregation: one wave per dst node, online segment softmax (f32 out) ----------
template <int C>
__launch_bounds__(256)
__global__ void gat_agg(const unsigned short* __restrict__ hg, const float* __restrict__ als,
                        const float* __restrict__ aldv, const int* __restrict__ rp,
                        const int* __restrict__ col, const float* __restrict__ biasf,
                        float* __restrict__ outv, const float* base,
                        int n, int self_loop, int act) {
  const int node = blockIdx.x * 4 + (threadIdx.x >> 6);
  if (node >= n) return;
  const int lane = threadIdx.x & 63;
  const float ald = aldv[node];
  float m = -INFINITY, den = 0.f, a0 = 0.f, a1 = 0.f;

  auto edge = [&](int s) {
    float l = als[s] + ald;
    l = (l > 0.f) ? l : 0.2f * l;  // LeakyReLU(0.2) on attention logit
    float w;
    if (l > m) {                   // wave-uniform (l, m identical across lanes)
      const float sc = __expf(m - l);
      den *= sc; a0 *= sc; a1 *= sc;
      m = l; w = 1.f;
    } else {
      w = __expf(l - m);
    }
    den += w;
    if constexpr (C == 128) {
      unsigned raw = *(const unsigned*)(hg + (size_t)s * 128 + 2 * lane);
      a0 = fmaf(w, __uint_as_float(raw << 16), a0);
      a1 = fmaf(w, __uint_as_float(raw & 0xFFFF0000u), a1);
    } else {
      a0 = fmaf(w, bf2f(hg[(size_t)s * C + lane]), a0);
    }
  };

  if (self_loop) edge(node);
  const int beg = rp[node], end = rp[node + 1];
  for (int p = beg; p < end; ++p) edge(__builtin_amdgcn_readfirstlane(col[p]));

  const float inv = 1.f / (den + 1e-16f);
  if constexpr (C == 128) {
    const size_t o = (size_t)node * 128 + 2 * lane;
    float2 bv = *(const float2*)(biasf + 2 * lane);
    float r0 = a0 * inv + bv.x;
    float r1 = a1 * inv + bv.y;
    if (base) { float2 bs = *(const float2*)(base + o); r0 += bs.x; r1 += bs.y; }
    if (act) {
      r0 = (r0 > 0.f) ? r0 : 0.01f * r0;
      r1 = (r1 > 0.f) ? r1 : 0.01f * r1;
    }
    *(float2*)(outv + o) = make_float2(r0, r1);
  } else {
    const size_t o = (size_t)node * C + lane;
    float r0 = a0 * inv + biasf[lane];
    if (base) r0 += base[o];
    if (act) r0 = (r0 > 0.f) ? r0 : 0.01f * r0;
    outv[o] = r0;
  }
}

extern "C" void kernel_launch(void* const* d_in, const int* in_sizes, int n_in,
                              void* d_out, int out_size, void* d_ws, size_t ws_size,
                              hipStream_t stream) {
  const int N = in_sizes[0] / 128;   // 100000
  const int E = in_sizes[1] / 2;     // 1600000

  const float* x    = (const float*)d_in[0];
  const int*   ei   = (const int*)d_in[1];
  const float* W0   = (const float*)d_in[2];
  const float* as0  = (const float*)d_in[3];
  const float* ad0  = (const float*)d_in[4];
  const float* b0   = (const float*)d_in[5];
  const float* slW0 = (const float*)d_in[6];
  const float* slb0 = (const float*)d_in[7];
  const float* W1   = (const float*)d_in[8];
  const float* as1  = (const float*)d_in[9];
  const float* ad1  = (const float*)d_in[10];
  const float* b1   = (const float*)d_in[11];
  const float* slW1 = (const float*)d_in[12];
  const float* slb1 = (const float*)d_in[13];
  const float* Wmu  = (const float*)d_in[14];
  const float* asmu = (const float*)d_in[15];
  const float* admu = (const float*)d_in[16];
  const float* bmu  = (const float*)d_in[17];
  const float* Wlv  = (const float*)d_in[18];
  const float* aslv = (const float*)d_in[19];
  const float* adlv = (const float*)d_in[20];
  const float* blv  = (const float*)d_in[21];

  // d_out is f32, 2*N*64 = N*128 floats (51.2 MB).
  // During layers 0/1 its space hosts hgB (bf16 N*128 = 25.6 MB), dead before heads write.
  float*          outF = (float*)d_out;
  unsigned short* hgB  = (unsigned short*)d_out;

  // workspace carve (~73 MB)
  char* w = (char*)d_ws;
  auto carve = [&](size_t bytes) -> char* {
    char* p = w;
    w += (bytes + 255) & ~(size_t)255;
    return p;
  };
  float*          h0   = (float*)carve((size_t)N * 128 * 4);          // 51.2 MB
  unsigned short* hgH  = (unsigned short*)carve((size_t)N * 64 * 2);  // 12.8 MB (head hg)
  float*          als  = (float*)carve((size_t)N * 4);
  float*          ald  = (float*)carve((size_t)N * 4);
  int*            cnt  = (int*)carve((size_t)N * 4);
  int*            rp   = (int*)carve((size_t)(N + 1) * 4);
  int*            cur  = (int*)carve((size_t)N * 4);
  int*            col  = (int*)carve((size_t)E * 4);                  // 6.4 MB
  int*            flag = (int*)carve(4);

  const int gE = (E + 255) / 256;
  const int gN = (N + 255) / 256;
  const int gG = (N + 63) / 64;   // gemm: 64 rows/block
  const int gW = (N + 3) / 4;     // wave-per-node: 4 nodes/block

  // --- edge layout probe + CSR (shared by all 4 convs) ---
  hipMemsetAsync(flag, 0, 4, stream);
  hipMemsetAsync(cnt, 0, (size_t)N * 4, stream);
  detect_kernel<<<1, 256, 0, stream>>>(ei, flag);
  hist_kernel<<<gE, 256, 0, stream>>>(ei, flag, cnt, E);
  scan_kernel<<<1, 1024, 0, stream>>>(cnt, rp, N);
  initcur_kernel<<<gN, 256, 0, stream>>>(rp, cur, N);
  fill_kernel<<<gE, 256, 0, stream>>>(ei, flag, cur, col, E);

  // --- layer 0: GATConv(no self loops) + Linear, LeakyReLU(0.01) ---
  gemm_k128<128, true><<<gG, 256, 0, stream>>>(x, W0, nullptr, hgB, N);
  gemm_k128<128, false><<<gG, 256, 0, stream>>>(x, slW0, slb0, h0, N);
  attn_logits<128><<<gW, 256, 0, stream>>>(hgB, as0, ad0, als, ald, N);
  gat_agg<128><<<gW, 256, 0, stream>>>(hgB, als, ald, rp, col, b0, h0, h0, N, 0, 1);

  // --- layer 1: GATConv(self loops) + Linear, LeakyReLU(0.01); h0 updated in place ---
  gemm_k128<128, true><<<gG, 256, 0, stream>>>(h0, W1, nullptr, hgB, N);
  gemm_k128<128, false><<<gG, 256, 0, stream>>>(h0, slW1, slb1, h0, N);  // in-place: block reads own rows before epilogue
  attn_logits<128><<<gW, 256, 0, stream>>>(hgB, as1, ad1, als, ald, N);
  gat_agg<128><<<gW, 256, 0, stream>>>(hgB, als, ald, rp, col, b1, h0, h0, N, 1, 1);

  // --- mu head (C=64, self loops, no act) -> outF[0 : N*64] ---
  gemm_k128<64, true><<<gG, 256, 0, stream>>>(h0, Wmu, nullptr, hgH, N);
  attn_logits<64><<<gW, 256, 0, stream>>>(hgH, asmu, admu, als, ald, N);
  gat_agg<64><<<gW, 256, 0, stream>>>(hgH, als, ald, rp, col, bmu,
                                      outF, nullptr, N, 1, 0);

  // --- logvar head -> outF[N*64 : 2*N*64] ---
  gemm_k128<64, true><<<gG, 256, 0, stream>>>(h0, Wlv, nullptr, hgH, N);
  attn_logits<64><<<gW, 256, 0, stream>>>(hgH, aslv, adlv, als, ald, N);
  gat_agg<64><<<gW, 256, 0, stream>>>(hgH, als, ald, rp, col, blv,
                                      outF + (size_t)N * 64, nullptr, N, 1, 0);
}

// Round 4
// 1066.820 us; speedup vs baseline: 1.4361x; 1.4361x over previous
//
#include <hip/hip_runtime.h>
#include <cstdint>
#include <cstddef>

// ---------- bf16 helpers (OCP bf16 = upper 16 bits of f32) ----------
__device__ __forceinline__ float bf2f(unsigned short u) {
  return __uint_as_float(((unsigned)u) << 16);
}
__device__ __forceinline__ unsigned short f2bf(float f) {
  unsigned u = __float_as_uint(f);
  u = (u + 0x7FFFu + ((u >> 16) & 1u)) >> 16;  // RNE
  return (unsigned short)u;
}

// ---------- edge_index layout probe ----------
__global__ void detect_kernel(const int* __restrict__ ei, int* __restrict__ flag) {
  int any = 0;
  for (int j = threadIdx.x; j < 4096; j += 256) any |= (ei[2 * j + 1] != 0);
  if (any) atomicOr(flag, 1);  // 1 => int32 layout
}

__device__ __forceinline__ int edge_src(const int* ei, int f, int e, int i) {
  return f ? ei[i] : ei[2 * (size_t)i];
}
__device__ __forceinline__ int edge_dst(const int* ei, int f, int e, int i) {
  return f ? ei[(size_t)e + i] : ei[2 * (size_t)e + 2 * (size_t)i];
}

// ---------- CSR build ----------
__global__ void hist_kernel(const int* __restrict__ ei, const int* __restrict__ flag,
                            int* __restrict__ cnt, int e) {
  int i = blockIdx.x * blockDim.x + threadIdx.x;
  if (i < e) atomicAdd(&cnt[edge_dst(ei, *flag, e, i)], 1);
}

// two-level scan: block scan (1024 el/block) -> top scan -> add offsets
__global__ void scan_block(const int* __restrict__ cnt, int* __restrict__ rp,
                           int* __restrict__ bsum, int n) {
  __shared__ int lds[256];
  const int t = threadIdx.x;
  const int base = blockIdx.x * 1024 + t * 4;
  int v0 = (base     < n) ? cnt[base]     : 0;
  int v1 = (base + 1 < n) ? cnt[base + 1] : 0;
  int v2 = (base + 2 < n) ? cnt[base + 2] : 0;
  int v3 = (base + 3 < n) ? cnt[base + 3] : 0;
  int s = v0 + v1 + v2 + v3;
  lds[t] = s;
  __syncthreads();
  for (int off = 1; off < 256; off <<= 1) {
    int y = (t >= off) ? lds[t - off] : 0;
    __syncthreads();
    lds[t] += y;
    __syncthreads();
  }
  int excl = lds[t] - s;
  if (base     < n) rp[base]     = excl;
  if (base + 1 < n) rp[base + 1] = excl + v0;
  if (base + 2 < n) rp[base + 2] = excl + v0 + v1;
  if (base + 3 < n) rp[base + 3] = excl + v0 + v1 + v2;
  if (t == 255) bsum[blockIdx.x] = lds[255];
}

__global__ void scan_tops(int* __restrict__ bsum, int* __restrict__ rp, int nb, int n) {
  __shared__ int lds[128];
  const int t = threadIdx.x;  // 128 threads, nb <= 128
  int v = (t < nb) ? bsum[t] : 0;
  lds[t] = v;
  __syncthreads();
  for (int off = 1; off < 128; off <<= 1) {
    int y = (t >= off) ? lds[t - off] : 0;
    __syncthreads();
    lds[t] += y;
    __syncthreads();
  }
  if (t < nb) bsum[t] = lds[t] - v;  // exclusive block offsets
  if (t == 127) rp[n] = lds[127];    // grand total
}

__global__ void scan_add(int* __restrict__ rp, const int* __restrict__ bsum, int n) {
  const int base = blockIdx.x * 1024 + threadIdx.x * 4;
  const int add = bsum[blockIdx.x];
#pragma unroll
  for (int i = 0; i < 4; ++i)
    if (base + i < n) rp[base + i] += add;
}

__global__ void initcur_kernel(const int* __restrict__ rp, int* __restrict__ cur, int n) {
  int i = blockIdx.x * blockDim.x + threadIdx.x;
  if (i < n) cur[i] = rp[i];
}

__global__ void fill_kernel(const int* __restrict__ ei, const int* __restrict__ flag,
                            int* __restrict__ cur, int* __restrict__ col, int e) {
  int i = blockIdx.x * blockDim.x + threadIdx.x;
  if (i < e) {
    int f = *flag;
    int s = edge_src(ei, f, e, i);
    int d = edge_dst(ei, f, e, i);
    int p = atomicAdd(&cur[d], 1);
    col[p] = s;
  }
}

// ---------- pack head weights: Whl[128][128] = [Wmu | Wlv] ----------
__global__ void pack_heads(const float* __restrict__ Wmu, const float* __restrict__ Wlv,
                           float* __restrict__ Whl) {
  int i = blockIdx.x * 256 + threadIdx.x;  // 128*64 = 8192
  if (i < 8192) {
    int r = i >> 6, c = i & 63;
    Whl[r * 128 + c]      = Wmu[i];
    Whl[r * 128 + 64 + c] = Wlv[i];
  }
}

// ---------- GEMM: Y[n,C] = X[n,128] @ W[128,C] (+bias), f32 in; Y f32 or bf16 ----------
template <int C, bool YBF>
__launch_bounds__(256)
__global__ void gemm_k128(const float* Xv, const float* __restrict__ Wf,
                          const float* __restrict__ biasf, void* Yv, int n) {
  constexpr int TC = C / 32;
  __shared__ float xs[64 * 32];
  __shared__ float wsm[32 * C];
  const int t = threadIdx.x;
  const int tc = t & 31;
  const int trg = t >> 5;
  const int row0 = blockIdx.x * 64;

  float acc[8][TC];
#pragma unroll
  for (int i = 0; i < 8; ++i)
#pragma unroll
    for (int c = 0; c < TC; ++c) acc[i][c] = 0.f;

  for (int kc = 0; kc < 128; kc += 32) {
    {
      const int r = t >> 2;
      const int j = (t & 3) * 8;
      const int row = row0 + r;
      float v[8];
      if (row < n) {
        const float* xp = Xv + (size_t)row * 128 + kc + j;
        float4 a = *(const float4*)xp;
        float4 b = *(const float4*)(xp + 4);
        v[0] = a.x; v[1] = a.y; v[2] = a.z; v[3] = a.w;
        v[4] = b.x; v[5] = b.y; v[6] = b.z; v[7] = b.w;
      } else {
#pragma unroll
        for (int q = 0; q < 8; ++q) v[q] = 0.f;
      }
      *(float4*)&xs[r * 32 + j]     = make_float4(v[0], v[1], v[2], v[3]);
      *(float4*)&xs[r * 32 + j + 4] = make_float4(v[4], v[5], v[6], v[7]);
    }
    {
      constexpr int per = (32 * C) / 256;
      const float* wp = Wf + (size_t)kc * C + t * per;
      float* wl = wsm + t * per;
#pragma unroll
      for (int q = 0; q < per; q += 4) *(float4*)(wl + q) = *(const float4*)(wp + q);
    }
    __syncthreads();
#pragma unroll
    for (int k = 0; k < 32; k += 4) {
      float wv[4][TC];
#pragma unroll
      for (int k2 = 0; k2 < 4; ++k2) {
        if constexpr (TC == 4) {
          float4 w4 = *(const float4*)&wsm[(k + k2) * C + tc * 4];
          wv[k2][0] = w4.x; wv[k2][1] = w4.y; wv[k2][2] = w4.z; wv[k2][3] = w4.w;
        } else {
          float2 w2 = *(const float2*)&wsm[(k + k2) * C + tc * 2];
          wv[k2][0] = w2.x; wv[k2][1] = w2.y;
        }
      }
#pragma unroll
      for (int i = 0; i < 8; ++i) {
        float4 x4 = *(const float4*)&xs[(trg * 8 + i) * 32 + k];
        float xa[4] = {x4.x, x4.y, x4.z, x4.w};
#pragma unroll
        for (int k2 = 0; k2 < 4; ++k2)
#pragma unroll
          for (int c = 0; c < TC; ++c)
            acc[i][c] = fmaf(xa[k2], wv[k2][c], acc[i][c]);
      }
    }
    __syncthreads();
  }
  float bv[TC];
#pragma unroll
  for (int c = 0; c < TC; ++c) bv[c] = biasf ? biasf[tc * TC + c] : 0.f;
#pragma unroll
  for (int i = 0; i < 8; ++i) {
    const int row = row0 + trg * 8 + i;
    if (row < n) {
      float r[TC];
#pragma unroll
      for (int c = 0; c < TC; ++c) r[c] = acc[i][c] + bv[c];
      if constexpr (YBF) {
        unsigned short* yp = (unsigned short*)Yv + (size_t)row * C + tc * TC;
        if constexpr (TC == 4) {
          uint2 u;
          u.x = (unsigned)f2bf(r[0]) | ((unsigned)f2bf(r[1]) << 16);
          u.y = (unsigned)f2bf(r[2]) | ((unsigned)f2bf(r[3]) << 16);
          *(uint2*)yp = u;
        } else {
          *(unsigned*)yp = (unsigned)f2bf(r[0]) | ((unsigned)f2bf(r[1]) << 16);
        }
      } else {
        float* yp = (float*)Yv + (size_t)row * C + tc * TC;
        if constexpr (TC == 4) *(float4*)yp = make_float4(r[0], r[1], r[2], r[3]);
        else                   *(float2*)yp = make_float2(r[0], r[1]);
      }
    }
  }
}

// ---------- per-node attention logits from bf16 hg (strided rows) ----------
template <int C>
__launch_bounds__(256)
__global__ void attn_logits2(const unsigned short* __restrict__ hg, int stride,
                             const float* __restrict__ asrc, const float* __restrict__ adst,
                             float* __restrict__ als, float* __restrict__ ald, int n) {
  const int node = blockIdx.x * 4 + (threadIdx.x >> 6);
  if (node >= n) return;
  const int lane = threadIdx.x & 63;
  float s, d;
  if constexpr (C == 128) {
    unsigned raw = *(const unsigned*)(hg + (size_t)node * stride + 2 * lane);
    float h0 = __uint_as_float(raw << 16);
    float h1 = __uint_as_float(raw & 0xFFFF0000u);
    float2 av = *(const float2*)(asrc + 2 * lane);
    float2 dv = *(const float2*)(adst + 2 * lane);
    s = h0 * av.x + h1 * av.y;
    d = h0 * dv.x + h1 * dv.y;
  } else {
    float h0 = bf2f(hg[(size_t)node * stride + lane]);
    s = h0 * asrc[lane];
    d = h0 * adst[lane];
  }
  for (int o = 32; o > 0; o >>= 1) {
    s += __shfl_xor(s, o, 64);
    d += __shfl_xor(d, o, 64);
  }
  if (lane == 0) { als[node] = s; ald[node] = d; }
}

// ---------- per-node segment-softmax max & inverse denominator ----------
__launch_bounds__(256)
__global__ void softmax_mden(const float* __restrict__ als, const float* __restrict__ aldv,
                             const int* __restrict__ rp, const int* __restrict__ col,
                             float* __restrict__ mArr, float* __restrict__ invD,
                             int n, int self_loop) {
  int i = blockIdx.x * blockDim.x + threadIdx.x;
  if (i >= n) return;
  const float ad = aldv[i];
  const int beg = rp[i], end = rp[i + 1];
  auto lk = [](float v) { return (v > 0.f) ? v : 0.2f * v; };
  float m = self_loop ? lk(als[i] + ad) : -INFINITY;
  for (int p = beg; p < end; ++p) m = fmaxf(m, lk(als[col[p]] + ad));
  float den = self_loop ? __expf(lk(als[i] + ad) - m) : 0.f;
  for (int p = beg; p < end; ++p) den += __expf(lk(als[col[p]] + ad) - m);
  mArr[i] = m;
  invD[i] = 1.f / (den + 1e-16f);
}

// ---------- aggregation: one wave per dst node, w precomputed => ILP-4 gathers ----------
template <int C>
__launch_bounds__(256)
__global__ void gat_agg2(const unsigned short* __restrict__ hg, int stride,
                         const float* __restrict__ als, const float* __restrict__ aldv,
                         const float* __restrict__ mArr, const float* __restrict__ invD,
                         const int* __restrict__ rp, const int* __restrict__ col,
                         const float* __restrict__ biasf, float* __restrict__ outv,
                         const float* base, int n, int self_loop, int act) {
  const int node = blockIdx.x * 4 + (threadIdx.x >> 6);
  if (node >= n) return;
  const int lane = threadIdx.x & 63;
  const float ad = aldv[node];
  const float mm = mArr[node];
  float a0 = 0.f, a1 = 0.f;

  auto wof = [&](int s) {
    float l = als[s] + ad;
    l = (l > 0.f) ? l : 0.2f * l;   // LeakyReLU(0.2)
    return __expf(l - mm);
  };
  auto addrow = [&](int s, float w) {
    if constexpr (C == 128) {
      unsigned raw = *(const unsigned*)(hg + (size_t)s * stride + 2 * lane);
      a0 = fmaf(w, __uint_as_float(raw << 16), a0);
      a1 = fmaf(w, __uint_as_float(raw & 0xFFFF0000u), a1);
    } else {
      a0 = fmaf(w, bf2f(hg[(size_t)s * stride + lane]), a0);
    }
  };

  if (self_loop) addrow(node, wof(node));
  const int beg = rp[node], end = rp[node + 1];
  int p = beg;
  for (; p + 4 <= end; p += 4) {
    int s0 = col[p], s1 = col[p + 1], s2 = col[p + 2], s3 = col[p + 3];
    float w0 = wof(s0), w1 = wof(s1), w2 = wof(s2), w3 = wof(s3);
    addrow(s0, w0); addrow(s1, w1); addrow(s2, w2); addrow(s3, w3);
  }
  for (; p < end; ++p) { int s = col[p]; addrow(s, wof(s)); }

  const float inv = invD[node];
  if constexpr (C == 128) {
    const size_t o = (size_t)node * 128 + 2 * lane;
    float2 bv = *(const float2*)(biasf + 2 * lane);
    float r0 = a0 * inv + bv.x;
    float r1 = a1 * inv + bv.y;
    if (base) { float2 bs = *(const float2*)(base + o); r0 += bs.x; r1 += bs.y; }
    if (act) {
      r0 = (r0 > 0.f) ? r0 : 0.01f * r0;
      r1 = (r1 > 0.f) ? r1 : 0.01f * r1;
    }
    *(float2*)(outv + o) = make_float2(r0, r1);
  } else {
    const size_t o = (size_t)node * 64 + lane;
    float r0 = a0 * inv + biasf[lane];
    if (base) r0 += base[o];
    if (act) r0 = (r0 > 0.f) ? r0 : 0.01f * r0;
    outv[o] = r0;
  }
}

extern "C" void kernel_launch(void* const* d_in, const int* in_sizes, int n_in,
                              void* d_out, int out_size, void* d_ws, size_t ws_size,
                              hipStream_t stream) {
  const int N = in_sizes[0] / 128;   // 100000
  const int E = in_sizes[1] / 2;     // 1600000

  const float* x    = (const float*)d_in[0];
  const int*   ei   = (const int*)d_in[1];
  const float* W0   = (const float*)d_in[2];
  const float* as0  = (const float*)d_in[3];
  const float* ad0  = (const float*)d_in[4];
  const float* b0   = (const float*)d_in[5];
  const float* slW0 = (const float*)d_in[6];
  const float* slb0 = (const float*)d_in[7];
  const float* W1   = (const float*)d_in[8];
  const float* as1  = (const float*)d_in[9];
  const float* ad1  = (const float*)d_in[10];
  const float* b1   = (const float*)d_in[11];
  const float* slW1 = (const float*)d_in[12];
  const float* slb1 = (const float*)d_in[13];
  const float* Wmu  = (const float*)d_in[14];
  const float* asmu = (const float*)d_in[15];
  const float* admu = (const float*)d_in[16];
  const float* bmu  = (const float*)d_in[17];
  const float* Wlv  = (const float*)d_in[18];
  const float* aslv = (const float*)d_in[19];
  const float* adlv = (const float*)d_in[20];
  const float* blv  = (const float*)d_in[21];

  float*          outF = (float*)d_out;
  unsigned short* hgB  = (unsigned short*)d_out;  // layers 0/1 hg lives in d_out (dead before heads write)

  // --- workspace plan: decide merged-head path by ws_size ---
  auto al = [](size_t b) { return (b + 255) & ~(size_t)255; };
  const size_t szH0  = al((size_t)N * 128 * 4);
  const size_t szHgM = al((size_t)N * 128 * 2);  // merged head hg [N][128] bf16
  const size_t szHgS = al((size_t)N * 64 * 2);   // fallback head hg [N][64] bf16
  const size_t szF   = al((size_t)N * 4);
  const size_t szRp  = al((size_t)(N + 1) * 4);
  const size_t szCol = al((size_t)E * 4);
  const size_t szWhl = al(128 * 128 * 4);
  const size_t fixed = szH0 + 6 * szF + szRp + szCol + 512 + 256;
  const bool merged = fixed + szHgM + szWhl <= ws_size;

  char* w = (char*)d_ws;
  auto carve = [&](size_t bytes) -> char* { char* p = w; w += al(bytes); return p; };
  float*          h0   = (float*)carve((size_t)N * 128 * 4);
  unsigned short* hgHd = (unsigned short*)carve(merged ? (size_t)N * 128 * 2 : (size_t)N * 64 * 2);
  float*          als  = (float*)carve((size_t)N * 4);
  float*          ald  = (float*)carve((size_t)N * 4);
  float*          mArr = (float*)carve((size_t)N * 4);
  float*          invD = (float*)carve((size_t)N * 4);
  int*            cnt  = (int*)carve((size_t)N * 4);
  int*            cur  = (int*)carve((size_t)N * 4);
  int*            rp   = (int*)carve((size_t)(N + 1) * 4);
  int*            col  = (int*)carve((size_t)E * 4);
  int*            bsum = (int*)carve(512);
  int*            flag = (int*)carve(4);
  float*          Whl  = merged ? (float*)carve(128 * 128 * 4) : nullptr;

  const int gE = (E + 255) / 256;
  const int gN = (N + 255) / 256;
  const int gG = (N + 63) / 64;       // gemm: 64 rows/block
  const int gW = (N + 3) / 4;         // wave-per-node: 4 nodes/block
  const int nb = (N + 1023) / 1024;   // scan blocks (98 <= 128)

  // --- edge layout probe + CSR ---
  hipMemsetAsync(flag, 0, 4, stream);
  hipMemsetAsync(cnt, 0, (size_t)N * 4, stream);
  detect_kernel<<<1, 256, 0, stream>>>(ei, flag);
  hist_kernel<<<gE, 256, 0, stream>>>(ei, flag, cnt, E);
  scan_block<<<nb, 256, 0, stream>>>(cnt, rp, bsum, N);
  scan_tops<<<1, 128, 0, stream>>>(bsum, rp, nb, N);
  scan_add<<<nb, 256, 0, stream>>>(rp, bsum, N);
  initcur_kernel<<<gN, 256, 0, stream>>>(rp, cur, N);
  fill_kernel<<<gE, 256, 0, stream>>>(ei, flag, cur, col, E);

  // --- layer 0: GATConv(no self loops) + Linear, LeakyReLU(0.01) ---
  gemm_k128<128, true><<<gG, 256, 0, stream>>>(x, W0, nullptr, hgB, N);
  gemm_k128<128, false><<<gG, 256, 0, stream>>>(x, slW0, slb0, h0, N);
  attn_logits2<128><<<gW, 256, 0, stream>>>(hgB, 128, as0, ad0, als, ald, N);
  softmax_mden<<<gN, 256, 0, stream>>>(als, ald, rp, col, mArr, invD, N, 0);
  gat_agg2<128><<<gW, 256, 0, stream>>>(hgB, 128, als, ald, mArr, invD, rp, col,
                                        b0, h0, h0, N, 0, 1);

  // --- layer 1: GATConv(self loops) + Linear, LeakyReLU(0.01); h0 in place ---
  gemm_k128<128, true><<<gG, 256, 0, stream>>>(h0, W1, nullptr, hgB, N);
  gemm_k128<128, false><<<gG, 256, 0, stream>>>(h0, slW1, slb1, h0, N);
  attn_logits2<128><<<gW, 256, 0, stream>>>(hgB, 128, as1, ad1, als, ald, N);
  softmax_mden<<<gN, 256, 0, stream>>>(als, ald, rp, col, mArr, invD, N, 1);
  gat_agg2<128><<<gW, 256, 0, stream>>>(hgB, 128, als, ald, mArr, invD, rp, col,
                                        b1, h0, h0, N, 1, 1);

  // --- heads ---
  if (merged) {
    pack_heads<<<32, 256, 0, stream>>>(Wmu, Wlv, Whl);
    gemm_k128<128, true><<<gG, 256, 0, stream>>>(h0, Whl, nullptr, hgHd, N);
    // mu
    attn_logits2<64><<<gW, 256, 0, stream>>>(hgHd, 128, asmu, admu, als, ald, N);
    softmax_mden<<<gN, 256, 0, stream>>>(als, ald, rp, col, mArr, invD, N, 1);
    gat_agg2<64><<<gW, 256, 0, stream>>>(hgHd, 128, als, ald, mArr, invD, rp, col,
                                         bmu, outF, nullptr, N, 1, 0);
    // logvar
    attn_logits2<64><<<gW, 256, 0, stream>>>(hgHd + 64, 128, aslv, adlv, als, ald, N);
    softmax_mden<<<gN, 256, 0, stream>>>(als, ald, rp, col, mArr, invD, N, 1);
    gat_agg2<64><<<gW, 256, 0, stream>>>(hgHd + 64, 128, als, ald, mArr, invD, rp, col,
                                         blv, outF + (size_t)N * 64, nullptr, N, 1, 0);
  } else {
    gemm_k128<64, true><<<gG, 256, 0, stream>>>(h0, Wmu, nullptr, hgHd, N);
    attn_logits2<64><<<gW, 256, 0, stream>>>(hgHd, 64, asmu, admu, als, ald, N);
    softmax_mden<<<gN, 256, 0, stream>>>(als, ald, rp, col, mArr, invD, N, 1);
    gat_agg2<64><<<gW, 256, 0, stream>>>(hgHd, 64, als, ald, mArr, invD, rp, col,
                                         bmu, outF, nullptr, N, 1, 0);
    gemm_k128<64, true><<<gG, 256, 0, stream>>>(h0, Wlv, nullptr, hgHd, N);
    attn_logits2<64><<<gW, 256, 0, stream>>>(hgHd, 64, aslv, adlv, als, ald, N);
    softmax_mden<<<gN, 256, 0, stream>>>(als, ald, rp, col, mArr, invD, N, 1);
    gat_agg2<64><<<gW, 256, 0, stream>>>(hgHd, 64, als, ald, mArr, invD, rp, col,
                                         blv, outF + (size_t)N * 64, nullptr, N, 1, 0);
  }
}

// Round 5
// 939.644 us; speedup vs baseline: 1.6304x; 1.1353x over previous
//
#include <hip/hip_runtime.h>
#include <cstdint>
#include <cstddef>

// ---------- bf16 helpers (OCP bf16 = upper 16 bits of f32) ----------
__device__ __forceinline__ float bf2f(unsigned short u) {
  return __uint_as_float(((unsigned)u) << 16);
}
__device__ __forceinline__ unsigned short f2bf(float f) {
  unsigned u = __float_as_uint(f);
  u = (u + 0x7FFFu + ((u >> 16) & 1u)) >> 16;  // RNE
  return (unsigned short)u;
}

// ---------- edge_index layout probe ----------
__global__ void detect_kernel(const int* __restrict__ ei, int* __restrict__ flag) {
  int any = 0;
  for (int j = threadIdx.x; j < 4096; j += 256) any |= (ei[2 * j + 1] != 0);
  if (any) atomicOr(flag, 1);  // 1 => int32 layout
}

__device__ __forceinline__ int edge_src(const int* ei, int f, int e, int i) {
  return f ? ei[i] : ei[2 * (size_t)i];
}
__device__ __forceinline__ int edge_dst(const int* ei, int f, int e, int i) {
  return f ? ei[(size_t)e + i] : ei[2 * (size_t)e + 2 * (size_t)i];
}

// ---------- CSR build ----------
__global__ void hist_kernel(const int* __restrict__ ei, const int* __restrict__ flag,
                            int* __restrict__ cnt, int e) {
  int i = blockIdx.x * blockDim.x + threadIdx.x;
  if (i < e) atomicAdd(&cnt[edge_dst(ei, *flag, e, i)], 1);
}

// two-level scan: block scan (1024 el/block) -> top scan -> add offsets
__global__ void scan_block(const int* __restrict__ cnt, int* __restrict__ rp,
                           int* __restrict__ bsum, int n) {
  __shared__ int lds[256];
  const int t = threadIdx.x;
  const int base = blockIdx.x * 1024 + t * 4;
  int v0 = (base     < n) ? cnt[base]     : 0;
  int v1 = (base + 1 < n) ? cnt[base + 1] : 0;
  int v2 = (base + 2 < n) ? cnt[base + 2] : 0;
  int v3 = (base + 3 < n) ? cnt[base + 3] : 0;
  int s = v0 + v1 + v2 + v3;
  lds[t] = s;
  __syncthreads();
  for (int off = 1; off < 256; off <<= 1) {
    int y = (t >= off) ? lds[t - off] : 0;
    __syncthreads();
    lds[t] += y;
    __syncthreads();
  }
  int excl = lds[t] - s;
  if (base     < n) rp[base]     = excl;
  if (base + 1 < n) rp[base + 1] = excl + v0;
  if (base + 2 < n) rp[base + 2] = excl + v0 + v1;
  if (base + 3 < n) rp[base + 3] = excl + v0 + v1 + v2;
  if (t == 255) bsum[blockIdx.x] = lds[255];
}

__global__ void scan_tops(int* __restrict__ bsum, int* __restrict__ rp, int nb, int n) {
  __shared__ int lds[128];
  const int t = threadIdx.x;  // 128 threads, nb <= 128
  int v = (t < nb) ? bsum[t] : 0;
  lds[t] = v;
  __syncthreads();
  for (int off = 1; off < 128; off <<= 1) {
    int y = (t >= off) ? lds[t - off] : 0;
    __syncthreads();
    lds[t] += y;
    __syncthreads();
  }
  if (t < nb) bsum[t] = lds[t] - v;
  if (t == 127) rp[n] = lds[127];
}

__global__ void scan_add(int* __restrict__ rp, const int* __restrict__ bsum, int n) {
  const int base = blockIdx.x * 1024 + threadIdx.x * 4;
  const int add = bsum[blockIdx.x];
#pragma unroll
  for (int i = 0; i < 4; ++i)
    if (base + i < n) rp[base + i] += add;
}

__global__ void initcur_kernel(const int* __restrict__ rp, int* __restrict__ cur, int n) {
  int i = blockIdx.x * blockDim.x + threadIdx.x;
  if (i < n) cur[i] = rp[i];
}

__global__ void fill_kernel(const int* __restrict__ ei, const int* __restrict__ flag,
                            int* __restrict__ cur, int* __restrict__ col, int e) {
  int i = blockIdx.x * blockDim.x + threadIdx.x;
  if (i < e) {
    int f = *flag;
    int s = edge_src(ei, f, e, i);
    int d = edge_dst(ei, f, e, i);
    int p = atomicAdd(&cur[d], 1);
    col[p] = s;
  }
}

// ---------- pack head weights: Whl[128][128] = [Wmu | Wlv] ----------
__global__ void pack_heads(const float* __restrict__ Wmu, const float* __restrict__ Wlv,
                           float* __restrict__ Whl) {
  int i = blockIdx.x * 256 + threadIdx.x;  // 128*64 = 8192
  if (i < 8192) {
    int r = i >> 6, c = i & 63;
    Whl[r * 128 + c]      = Wmu[i];
    Whl[r * 128 + 64 + c] = Wlv[i];
  }
}

// ---------- GEMM: Y[n,C] = X[n,128] @ W[128,C] (+bias), f32 in; Y f32 or bf16 ----------
template <int C, bool YBF>
__launch_bounds__(256)
__global__ void gemm_k128(const float* Xv, const float* __restrict__ Wf,
                          const float* __restrict__ biasf, void* Yv, int n) {
  constexpr int TC = C / 32;
  __shared__ float xs[64 * 32];
  __shared__ float wsm[32 * C];
  const int t = threadIdx.x;
  const int tc = t & 31;
  const int trg = t >> 5;
  const int row0 = blockIdx.x * 64;

  float acc[8][TC];
#pragma unroll
  for (int i = 0; i < 8; ++i)
#pragma unroll
    for (int c = 0; c < TC; ++c) acc[i][c] = 0.f;

  for (int kc = 0; kc < 128; kc += 32) {
    {
      const int r = t >> 2;
      const int j = (t & 3) * 8;
      const int row = row0 + r;
      float v[8];
      if (row < n) {
        const float* xp = Xv + (size_t)row * 128 + kc + j;
        float4 a = *(const float4*)xp;
        float4 b = *(const float4*)(xp + 4);
        v[0] = a.x; v[1] = a.y; v[2] = a.z; v[3] = a.w;
        v[4] = b.x; v[5] = b.y; v[6] = b.z; v[7] = b.w;
      } else {
#pragma unroll
        for (int q = 0; q < 8; ++q) v[q] = 0.f;
      }
      *(float4*)&xs[r * 32 + j]     = make_float4(v[0], v[1], v[2], v[3]);
      *(float4*)&xs[r * 32 + j + 4] = make_float4(v[4], v[5], v[6], v[7]);
    }
    {
      constexpr int per = (32 * C) / 256;
      const float* wp = Wf + (size_t)kc * C + t * per;
      float* wl = wsm + t * per;
#pragma unroll
      for (int q = 0; q < per; q += 4) *(float4*)(wl + q) = *(const float4*)(wp + q);
    }
    __syncthreads();
#pragma unroll
    for (int k = 0; k < 32; k += 4) {
      float wv[4][TC];
#pragma unroll
      for (int k2 = 0; k2 < 4; ++k2) {
        if constexpr (TC == 4) {
          float4 w4 = *(const float4*)&wsm[(k + k2) * C + tc * 4];
          wv[k2][0] = w4.x; wv[k2][1] = w4.y; wv[k2][2] = w4.z; wv[k2][3] = w4.w;
        } else {
          float2 w2 = *(const float2*)&wsm[(k + k2) * C + tc * 2];
          wv[k2][0] = w2.x; wv[k2][1] = w2.y;
        }
      }
#pragma unroll
      for (int i = 0; i < 8; ++i) {
        float4 x4 = *(const float4*)&xs[(trg * 8 + i) * 32 + k];
        float xa[4] = {x4.x, x4.y, x4.z, x4.w};
#pragma unroll
        for (int k2 = 0; k2 < 4; ++k2)
#pragma unroll
          for (int c = 0; c < TC; ++c)
            acc[i][c] = fmaf(xa[k2], wv[k2][c], acc[i][c]);
      }
    }
    __syncthreads();
  }
  float bv[TC];
#pragma unroll
  for (int c = 0; c < TC; ++c) bv[c] = biasf ? biasf[tc * TC + c] : 0.f;
#pragma unroll
  for (int i = 0; i < 8; ++i) {
    const int row = row0 + trg * 8 + i;
    if (row < n) {
      float r[TC];
#pragma unroll
      for (int c = 0; c < TC; ++c) r[c] = acc[i][c] + bv[c];
      if constexpr (YBF) {
        unsigned short* yp = (unsigned short*)Yv + (size_t)row * C + tc * TC;
        if constexpr (TC == 4) {
          uint2 u;
          u.x = (unsigned)f2bf(r[0]) | ((unsigned)f2bf(r[1]) << 16);
          u.y = (unsigned)f2bf(r[2]) | ((unsigned)f2bf(r[3]) << 16);
          *(uint2*)yp = u;
        } else {
          *(unsigned*)yp = (unsigned)f2bf(r[0]) | ((unsigned)f2bf(r[1]) << 16);
        }
      } else {
        float* yp = (float*)Yv + (size_t)row * C + tc * TC;
        if constexpr (TC == 4) *(float4*)yp = make_float4(r[0], r[1], r[2], r[3]);
        else                   *(float2*)yp = make_float2(r[0], r[1]);
      }
    }
  }
}

// ---------- per-node attention logits from bf16 hg (strided rows) ----------
template <int C>
__launch_bounds__(256)
__global__ void attn_logits2(const unsigned short* __restrict__ hg, int stride,
                             const float* __restrict__ asrc, const float* __restrict__ adst,
                             float* __restrict__ als, float* __restrict__ ald, int n) {
  const int node = blockIdx.x * 4 + (threadIdx.x >> 6);
  if (node >= n) return;
  const int lane = threadIdx.x & 63;
  float s, d;
  if constexpr (C == 128) {
    unsigned raw = *(const unsigned*)(hg + (size_t)node * stride + 2 * lane);
    float h0 = __uint_as_float(raw << 16);
    float h1 = __uint_as_float(raw & 0xFFFF0000u);
    float2 av = *(const float2*)(asrc + 2 * lane);
    float2 dv = *(const float2*)(adst + 2 * lane);
    s = h0 * av.x + h1 * av.y;
    d = h0 * dv.x + h1 * dv.y;
  } else {
    float h0 = bf2f(hg[(size_t)node * stride + lane]);
    s = h0 * asrc[lane];
    d = h0 * adst[lane];
  }
  for (int o = 32; o > 0; o >>= 1) {
    s += __shfl_xor(s, o, 64);
    d += __shfl_xor(d, o, 64);
  }
  if (lane == 0) { als[node] = s; ald[node] = d; }
}

// ---------- fused aggregation: one wave per node, lane-parallel softmax ----------
// Edge list for node = [col[beg..end), (node if self_loop)]; lane j handles entry j
// of each 64-wide chunk. Online rescale across chunks (deg>64 safe; deg=0 -> out=bias+base).
template <int C>
__launch_bounds__(256)
__global__ void gat_agg3(const unsigned short* __restrict__ hg, int stride,
                         const float* __restrict__ als, const float* __restrict__ aldv,
                         const int* __restrict__ rp, const int* __restrict__ col,
                         const float* __restrict__ biasf, float* __restrict__ outv,
                         const float* base, int n, int self_loop, int act) {
  const int node = blockIdx.x * 4 + (threadIdx.x >> 6);
  if (node >= n) return;
  const int lane = threadIdx.x & 63;
  const int beg = rp[node];
  const int deg = rp[node + 1] - beg;
  const int total = deg + self_loop;
  const float ad = aldv[node];

  float m = -INFINITY, den = 0.f, a0 = 0.f, a1 = 0.f;

  for (int cb = 0; cb < total; cb += 64) {
    const int idx = cb + lane;
    const bool valid = idx < total;
    int s = node;
    if (valid && idx < deg) s = col[beg + idx];
    float l = -INFINITY;
    if (valid) {
      float v = als[s] + ad;
      l = (v > 0.f) ? v : 0.2f * v;  // LeakyReLU(0.2)
    }
    // wave max of l
    float cm = l;
#pragma unroll
    for (int o = 32; o > 0; o >>= 1) cm = fmaxf(cm, __shfl_xor(cm, o, 64));
    const float newm = fmaxf(m, cm);
    const float scale = __expf(m - newm);  // m=-INF (first chunk) -> 0
    den *= scale; a0 *= scale; a1 *= scale;
    m = newm;
    const float e = valid ? __expf(l - m) : 0.f;
    float cd = e;
#pragma unroll
    for (int o = 32; o > 0; o >>= 1) cd += __shfl_xor(cd, o, 64);
    den += cd;

    const int cnt = (total - cb < 64) ? (total - cb) : 64;
    int j = 0;
    for (; j + 4 <= cnt; j += 4) {
      float w0 = __shfl(e, j, 64),     w1 = __shfl(e, j + 1, 64);
      float w2 = __shfl(e, j + 2, 64), w3 = __shfl(e, j + 3, 64);
      int s0 = __shfl(s, j, 64),     s1 = __shfl(s, j + 1, 64);
      int s2 = __shfl(s, j + 2, 64), s3 = __shfl(s, j + 3, 64);
      if constexpr (C == 128) {
        unsigned r0 = *(const unsigned*)(hg + (size_t)s0 * stride + 2 * lane);
        unsigned r1 = *(const unsigned*)(hg + (size_t)s1 * stride + 2 * lane);
        unsigned r2 = *(const unsigned*)(hg + (size_t)s2 * stride + 2 * lane);
        unsigned r3 = *(const unsigned*)(hg + (size_t)s3 * stride + 2 * lane);
        a0 = fmaf(w0, __uint_as_float(r0 << 16), a0);
        a1 = fmaf(w0, __uint_as_float(r0 & 0xFFFF0000u), a1);
        a0 = fmaf(w1, __uint_as_float(r1 << 16), a0);
        a1 = fmaf(w1, __uint_as_float(r1 & 0xFFFF0000u), a1);
        a0 = fmaf(w2, __uint_as_float(r2 << 16), a0);
        a1 = fmaf(w2, __uint_as_float(r2 & 0xFFFF0000u), a1);
        a0 = fmaf(w3, __uint_as_float(r3 << 16), a0);
        a1 = fmaf(w3, __uint_as_float(r3 & 0xFFFF0000u), a1);
      } else {
        float h0 = bf2f(hg[(size_t)s0 * stride + lane]);
        float h1 = bf2f(hg[(size_t)s1 * stride + lane]);
        float h2 = bf2f(hg[(size_t)s2 * stride + lane]);
        float h3 = bf2f(hg[(size_t)s3 * stride + lane]);
        a0 = fmaf(w0, h0, a0); a0 = fmaf(w1, h1, a0);
        a0 = fmaf(w2, h2, a0); a0 = fmaf(w3, h3, a0);
      }
    }
    for (; j < cnt; ++j) {
      float wj = __shfl(e, j, 64);
      int sj = __shfl(s, j, 64);
      if constexpr (C == 128) {
        unsigned raw = *(const unsigned*)(hg + (size_t)sj * stride + 2 * lane);
        a0 = fmaf(wj, __uint_as_float(raw << 16), a0);
        a1 = fmaf(wj, __uint_as_float(raw & 0xFFFF0000u), a1);
      } else {
        a0 = fmaf(wj, bf2f(hg[(size_t)sj * stride + lane]), a0);
      }
    }
  }

  const float inv = 1.f / (den + 1e-16f);
  if constexpr (C == 128) {
    const size_t o = (size_t)node * 128 + 2 * lane;
    float2 bv = *(const float2*)(biasf + 2 * lane);
    float r0 = a0 * inv + bv.x;
    float r1 = a1 * inv + bv.y;
    if (base) { float2 bs = *(const float2*)(base + o); r0 += bs.x; r1 += bs.y; }
    if (act) {
      r0 = (r0 > 0.f) ? r0 : 0.01f * r0;
      r1 = (r1 > 0.f) ? r1 : 0.01f * r1;
    }
    *(float2*)(outv + o) = make_float2(r0, r1);
  } else {
    const size_t o = (size_t)node * 64 + lane;
    float r0 = a0 * inv + biasf[lane];
    if (base) r0 += base[o];
    if (act) r0 = (r0 > 0.f) ? r0 : 0.01f * r0;
    outv[o] = r0;
  }
}

extern "C" void kernel_launch(void* const* d_in, const int* in_sizes, int n_in,
                              void* d_out, int out_size, void* d_ws, size_t ws_size,
                              hipStream_t stream) {
  const int N = in_sizes[0] / 128;   // 100000
  const int E = in_sizes[1] / 2;     // 1600000

  const float* x    = (const float*)d_in[0];
  const int*   ei   = (const int*)d_in[1];
  const float* W0   = (const float*)d_in[2];
  const float* as0  = (const float*)d_in[3];
  const float* ad0  = (const float*)d_in[4];
  const float* b0   = (const float*)d_in[5];
  const float* slW0 = (const float*)d_in[6];
  const float* slb0 = (const float*)d_in[7];
  const float* W1   = (const float*)d_in[8];
  const float* as1  = (const float*)d_in[9];
  const float* ad1  = (const float*)d_in[10];
  const float* b1   = (const float*)d_in[11];
  const float* slW1 = (const float*)d_in[12];
  const float* slb1 = (const float*)d_in[13];
  const float* Wmu  = (const float*)d_in[14];
  const float* asmu = (const float*)d_in[15];
  const float* admu = (const float*)d_in[16];
  const float* bmu  = (const float*)d_in[17];
  const float* Wlv  = (const float*)d_in[18];
  const float* aslv = (const float*)d_in[19];
  const float* adlv = (const float*)d_in[20];
  const float* blv  = (const float*)d_in[21];

  float*          outF = (float*)d_out;
  unsigned short* hgB  = (unsigned short*)d_out;  // layers 0/1 hg lives in d_out

  auto al = [](size_t b) { return (b + 255) & ~(size_t)255; };
  const size_t szH0  = al((size_t)N * 128 * 4);
  const size_t szHgM = al((size_t)N * 128 * 2);
  const size_t szF   = al((size_t)N * 4);
  const size_t szRp  = al((size_t)(N + 1) * 4);
  const size_t szCol = al((size_t)E * 4);
  const size_t szWhl = al(128 * 128 * 4);
  const size_t fixed = szH0 + 4 * szF + szRp + szCol + 512 + 256;
  const bool merged = fixed + szHgM + szWhl <= ws_size;

  char* w = (char*)d_ws;
  auto carve = [&](size_t bytes) -> char* { char* p = w; w += al(bytes); return p; };
  float*          h0   = (float*)carve((size_t)N * 128 * 4);
  unsigned short* hgHd = (unsigned short*)carve(merged ? (size_t)N * 128 * 2 : (size_t)N * 64 * 2);
  float*          als  = (float*)carve((size_t)N * 4);
  float*          ald  = (float*)carve((size_t)N * 4);
  int*            cnt  = (int*)carve((size_t)N * 4);
  int*            cur  = (int*)carve((size_t)N * 4);
  int*            rp   = (int*)carve((size_t)(N + 1) * 4);
  int*            col  = (int*)carve((size_t)E * 4);
  int*            bsum = (int*)carve(512);
  int*            flag = (int*)carve(4);
  float*          Whl  = merged ? (float*)carve(128 * 128 * 4) : nullptr;

  const int gE = (E + 255) / 256;
  const int gN = (N + 255) / 256;
  const int gG = (N + 63) / 64;
  const int gW = (N + 3) / 4;
  const int nb = (N + 1023) / 1024;

  // --- edge layout probe + CSR ---
  hipMemsetAsync(flag, 0, 4, stream);
  hipMemsetAsync(cnt, 0, (size_t)N * 4, stream);
  detect_kernel<<<1, 256, 0, stream>>>(ei, flag);
  hist_kernel<<<gE, 256, 0, stream>>>(ei, flag, cnt, E);
  scan_block<<<nb, 256, 0, stream>>>(cnt, rp, bsum, N);
  scan_tops<<<1, 128, 0, stream>>>(bsum, rp, nb, N);
  scan_add<<<nb, 256, 0, stream>>>(rp, bsum, N);
  initcur_kernel<<<gN, 256, 0, stream>>>(rp, cur, N);
  fill_kernel<<<gE, 256, 0, stream>>>(ei, flag, cur, col, E);

  // --- layer 0: GATConv(no self loops) + Linear, LeakyReLU(0.01) ---
  gemm_k128<128, true><<<gG, 256, 0, stream>>>(x, W0, nullptr, hgB, N);
  gemm_k128<128, false><<<gG, 256, 0, stream>>>(x, slW0, slb0, h0, N);
  attn_logits2<128><<<gW, 256, 0, stream>>>(hgB, 128, as0, ad0, als, ald, N);
  gat_agg3<128><<<gW, 256, 0, stream>>>(hgB, 128, als, ald, rp, col, b0, h0, h0, N, 0, 1);

  // --- layer 1: GATConv(self loops) + Linear, LeakyReLU(0.01); h0 in place ---
  gemm_k128<128, true><<<gG, 256, 0, stream>>>(h0, W1, nullptr, hgB, N);
  gemm_k128<128, false><<<gG, 256, 0, stream>>>(h0, slW1, slb1, h0, N);
  attn_logits2<128><<<gW, 256, 0, stream>>>(hgB, 128, as1, ad1, als, ald, N);
  gat_agg3<128><<<gW, 256, 0, stream>>>(hgB, 128, als, ald, rp, col, b1, h0, h0, N, 1, 1);

  // --- heads ---
  if (merged) {
    pack_heads<<<32, 256, 0, stream>>>(Wmu, Wlv, Whl);
    gemm_k128<128, true><<<gG, 256, 0, stream>>>(h0, Whl, nullptr, hgHd, N);
    attn_logits2<64><<<gW, 256, 0, stream>>>(hgHd, 128, asmu, admu, als, ald, N);
    gat_agg3<64><<<gW, 256, 0, stream>>>(hgHd, 128, als, ald, rp, col, bmu,
                                         outF, nullptr, N, 1, 0);
    attn_logits2<64><<<gW, 256, 0, stream>>>(hgHd + 64, 128, aslv, adlv, als, ald, N);
    gat_agg3<64><<<gW, 256, 0, stream>>>(hgHd + 64, 128, als, ald, rp, col, blv,
                                         outF + (size_t)N * 64, nullptr, N, 1, 0);
  } else {
    gemm_k128<64, true><<<gG, 256, 0, stream>>>(h0, Wmu, nullptr, hgHd, N);
    attn_logits2<64><<<gW, 256, 0, stream>>>(hgHd, 64, asmu, admu, als, ald, N);
    gat_agg3<64><<<gW, 256, 0, stream>>>(hgHd, 64, als, ald, rp, col, bmu,
                                         outF, nullptr, N, 1, 0);
    gemm_k128<64, true><<<gG, 256, 0, stream>>>(h0, Wlv, nullptr, hgHd, N);
    attn_logits2<64><<<gW, 256, 0, stream>>>(hgHd, 64, aslv, adlv, als, ald, N);
    gat_agg3<64><<<gW, 256, 0, stream>>>(hgHd, 64, als, ald, rp, col, blv,
                                         outF + (size_t)N * 64, nullptr, N, 1, 0);
  }
}

// Round 6
// 906.314 us; speedup vs baseline: 1.6904x; 1.0368x over previous
//
#include <hip/hip_runtime.h>
#include <cstdint>
#include <cstddef>

// ---------- bf16 helpers (OCP bf16 = upper 16 bits of f32) ----------
__device__ __forceinline__ float bf2f(unsigned short u) {
  return __uint_as_float(((unsigned)u) << 16);
}
__device__ __forceinline__ unsigned short f2bf(float f) {
  unsigned u = __float_as_uint(f);
  u = (u + 0x7FFFu + ((u >> 16) & 1u)) >> 16;  // RNE
  return (unsigned short)u;
}

// ---------- edge_index layout probe ----------
__global__ void detect_kernel(const int* __restrict__ ei, int* __restrict__ flag) {
  int any = 0;
  for (int j = threadIdx.x; j < 4096; j += 256) any |= (ei[2 * j + 1] != 0);
  if (any) atomicOr(flag, 1);  // 1 => int32 layout
}

__device__ __forceinline__ int edge_src(const int* ei, int f, int e, int i) {
  return f ? ei[i] : ei[2 * (size_t)i];
}
__device__ __forceinline__ int edge_dst(const int* ei, int f, int e, int i) {
  return f ? ei[(size_t)e + i] : ei[2 * (size_t)e + 2 * (size_t)i];
}

// ---------- per-node degree histogram ----------
__global__ void hist_kernel(const int* __restrict__ ei, const int* __restrict__ flag,
                            int* __restrict__ cnt, int e) {
  int i = blockIdx.x * blockDim.x + threadIdx.x;
  if (i < e) atomicAdd(&cnt[edge_dst(ei, *flag, e, i)], 1);
}

// two-level scan for rp
__global__ void scan_block(const int* __restrict__ cnt, int* __restrict__ rp,
                           int* __restrict__ bsum, int n) {
  __shared__ int lds[256];
  const int t = threadIdx.x;
  const int base = blockIdx.x * 1024 + t * 4;
  int v0 = (base     < n) ? cnt[base]     : 0;
  int v1 = (base + 1 < n) ? cnt[base + 1] : 0;
  int v2 = (base + 2 < n) ? cnt[base + 2] : 0;
  int v3 = (base + 3 < n) ? cnt[base + 3] : 0;
  int s = v0 + v1 + v2 + v3;
  lds[t] = s;
  __syncthreads();
  for (int off = 1; off < 256; off <<= 1) {
    int y = (t >= off) ? lds[t - off] : 0;
    __syncthreads();
    lds[t] += y;
    __syncthreads();
  }
  int excl = lds[t] - s;
  if (base     < n) rp[base]     = excl;
  if (base + 1 < n) rp[base + 1] = excl + v0;
  if (base + 2 < n) rp[base + 2] = excl + v0 + v1;
  if (base + 3 < n) rp[base + 3] = excl + v0 + v1 + v2;
  if (t == 255) bsum[blockIdx.x] = lds[255];
}

__global__ void scan_tops(int* __restrict__ bsum, int* __restrict__ rp, int nb, int n) {
  __shared__ int lds[128];
  const int t = threadIdx.x;
  int v = (t < nb) ? bsum[t] : 0;
  lds[t] = v;
  __syncthreads();
  for (int off = 1; off < 128; off <<= 1) {
    int y = (t >= off) ? lds[t - off] : 0;
    __syncthreads();
    lds[t] += y;
    __syncthreads();
  }
  if (t < nb) bsum[t] = lds[t] - v;
  if (t == 127) rp[n] = lds[127];
}

__global__ void scan_add(int* __restrict__ rp, const int* __restrict__ bsum, int n) {
  const int base = blockIdx.x * 1024 + threadIdx.x * 4;
  const int add = bsum[blockIdx.x];
#pragma unroll
  for (int i = 0; i < 4; ++i)
    if (base + i < n) rp[base + i] += add;
}

// ---------- bucketed CSR fill (kills scatter write-amp) ----------
// NB=128 buckets of W=(N+127)/128 consecutive nodes. bucket(d) = d / W.
#define NB 128

__global__ void bucket_hist(const int* __restrict__ ei, const int* __restrict__ flag,
                            int* __restrict__ bhist, int e, int W) {
  __shared__ int lh[NB];
  const int t = threadIdx.x;
  if (t < NB) lh[t] = 0;
  __syncthreads();
  const int base = blockIdx.x * 4096;
  const int f = *flag;
  for (int j = t; j < 4096; j += 256) {
    int i = base + j;
    if (i < e) atomicAdd(&lh[edge_dst(ei, f, e, i) / W], 1);
  }
  __syncthreads();
  if (t < NB && lh[t]) atomicAdd(&bhist[t], lh[t]);
}

__global__ void bucket_scan(const int* __restrict__ bhist, int* __restrict__ boffs,
                            int* __restrict__ bcur) {
  __shared__ int lds[NB];
  const int t = threadIdx.x;  // 128 threads
  int v = bhist[t];
  lds[t] = v;
  __syncthreads();
  for (int off = 1; off < NB; off <<= 1) {
    int y = (t >= off) ? lds[t - off] : 0;
    __syncthreads();
    lds[t] += y;
    __syncthreads();
  }
  int excl = lds[t] - v;
  boffs[t] = excl;
  bcur[t] = excl;
  if (t == NB - 1) boffs[NB] = lds[NB - 1];
}

// scatter (src,dst) pairs into bucket-contiguous ebuf; per-block windows are
// small & exclusive -> L2 accumulates full lines, writeback ~= useful bytes
__global__ void bucket_scatter(const int* __restrict__ ei, const int* __restrict__ flag,
                               int* __restrict__ bcur, int2* __restrict__ ebuf,
                               int e, int W) {
  __shared__ int lh[NB];
  __shared__ int lbase[NB];
  const int t = threadIdx.x;
  if (t < NB) lh[t] = 0;
  __syncthreads();
  const int base = blockIdx.x * 4096;
  const int f = *flag;
  for (int j = t; j < 4096; j += 256) {
    int i = base + j;
    if (i < e) atomicAdd(&lh[edge_dst(ei, f, e, i) / W], 1);
  }
  __syncthreads();
  if (t < NB) {
    lbase[t] = lh[t] ? atomicAdd(&bcur[t], lh[t]) : 0;
    lh[t] = 0;
  }
  __syncthreads();
  for (int j = t; j < 4096; j += 256) {
    int i = base + j;
    if (i < e) {
      int d = edge_dst(ei, f, e, i);
      int s = edge_src(ei, f, e, i);
      int b = d / W;
      int off = atomicAdd(&lh[b], 1);
      ebuf[lbase[b] + off] = make_int2(s, d);
    }
  }
}

// one block per bucket: LDS cursors, col writes land in a block-exclusive window
__global__ void bucket_fill(const int2* __restrict__ ebuf, const int* __restrict__ boffs,
                            const int* __restrict__ rp, int* __restrict__ col,
                            int n, int W) {
  __shared__ int cur[1024];  // W <= 1024
  const int b = blockIdx.x;
  const int lo = b * W;
  const int nn = min(W, n - lo);
  if (nn <= 0) return;
  for (int i = threadIdx.x; i < nn; i += 256) cur[i] = rp[lo + i];
  __syncthreads();
  const int beg = boffs[b], end = boffs[b + 1];
  for (int p = beg + threadIdx.x; p < end; p += 256) {
    int2 sd = ebuf[p];
    int pos = atomicAdd(&cur[sd.y - lo], 1);
    col[pos] = sd.x;
  }
}

// ---------- weight packing ----------
__global__ void pack_heads(const float* __restrict__ Wmu, const float* __restrict__ Wlv,
                           float* __restrict__ Whl) {
  int i = blockIdx.x * 256 + threadIdx.x;  // 128*64
  if (i < 8192) {
    int r = i >> 6, c = i & 63;
    Whl[r * 128 + c]      = Wmu[i];
    Whl[r * 128 + 64 + c] = Wlv[i];
  }
}

// Wd[128][256] = [Wg | Wsl]
__global__ void pack_dual(const float* __restrict__ Wg, const float* __restrict__ Wsl,
                          float* __restrict__ Wd) {
  int i = blockIdx.x * 256 + threadIdx.x;  // 128*128 = 16384 per half
  if (i < 16384) {
    int r = i >> 7, c = i & 127;
    Wd[r * 256 + c]       = Wg[i];
    Wd[r * 256 + 128 + c] = Wsl[i];
  }
}

// ---------- dual GEMM: hg(bf16) = X@Wg ; h(f32) = X@Wsl + bias ----------
__launch_bounds__(256)
__global__ void gemm_dual(const float* Xv, const float* __restrict__ Wd,
                          const float* __restrict__ bias2,
                          unsigned short* __restrict__ Yb, float* Yf, int n) {
  __shared__ float xs[64 * 32];     // 8 KB
  __shared__ float wsm[32 * 256];   // 32 KB
  const int t = threadIdx.x;
  const int tc = t & 31;
  const int trg = t >> 5;
  const int row0 = blockIdx.x * 64;

  float acc[8][8];
#pragma unroll
  for (int i = 0; i < 8; ++i)
#pragma unroll
    for (int c = 0; c < 8; ++c) acc[i][c] = 0.f;

  for (int kc = 0; kc < 128; kc += 32) {
    {
      const int r = t >> 2;
      const int j = (t & 3) * 8;
      const int row = row0 + r;
      float v[8];
      if (row < n) {
        const float* xp = Xv + (size_t)row * 128 + kc + j;
        float4 a = *(const float4*)xp;
        float4 b = *(const float4*)(xp + 4);
        v[0] = a.x; v[1] = a.y; v[2] = a.z; v[3] = a.w;
        v[4] = b.x; v[5] = b.y; v[6] = b.z; v[7] = b.w;
      } else {
#pragma unroll
        for (int q = 0; q < 8; ++q) v[q] = 0.f;
      }
      *(float4*)&xs[r * 32 + j]     = make_float4(v[0], v[1], v[2], v[3]);
      *(float4*)&xs[r * 32 + j + 4] = make_float4(v[4], v[5], v[6], v[7]);
    }
    {
      const float* wp = Wd + (size_t)kc * 256 + t * 32;
      float* wl = wsm + t * 32;
#pragma unroll
      for (int q = 0; q < 32; q += 4) *(float4*)(wl + q) = *(const float4*)(wp + q);
    }
    __syncthreads();
#pragma unroll
    for (int k = 0; k < 32; k += 4) {
      float wv[4][8];
#pragma unroll
      for (int k2 = 0; k2 < 4; ++k2) {
        float4 wa = *(const float4*)&wsm[(k + k2) * 256 + tc * 8];
        float4 wb = *(const float4*)&wsm[(k + k2) * 256 + tc * 8 + 4];
        wv[k2][0] = wa.x; wv[k2][1] = wa.y; wv[k2][2] = wa.z; wv[k2][3] = wa.w;
        wv[k2][4] = wb.x; wv[k2][5] = wb.y; wv[k2][6] = wb.z; wv[k2][7] = wb.w;
      }
#pragma unroll
      for (int i = 0; i < 8; ++i) {
        float4 x4 = *(const float4*)&xs[(trg * 8 + i) * 32 + k];
        float xa[4] = {x4.x, x4.y, x4.z, x4.w};
#pragma unroll
        for (int k2 = 0; k2 < 4; ++k2)
#pragma unroll
          for (int c = 0; c < 8; ++c)
            acc[i][c] = fmaf(xa[k2], wv[k2][c], acc[i][c]);
      }
    }
    __syncthreads();
  }
  // epilogue: tc<16 -> hg cols (bf16), tc>=16 -> h cols (f32, +bias)
  if (tc < 16) {
#pragma unroll
    for (int i = 0; i < 8; ++i) {
      const int row = row0 + trg * 8 + i;
      if (row < n) {
        unsigned short* yp = Yb + (size_t)row * 128 + tc * 8;
        uint4 u;
        u.x = (unsigned)f2bf(acc[i][0]) | ((unsigned)f2bf(acc[i][1]) << 16);
        u.y = (unsigned)f2bf(acc[i][2]) | ((unsigned)f2bf(acc[i][3]) << 16);
        u.z = (unsigned)f2bf(acc[i][4]) | ((unsigned)f2bf(acc[i][5]) << 16);
        u.w = (unsigned)f2bf(acc[i][6]) | ((unsigned)f2bf(acc[i][7]) << 16);
        *(uint4*)yp = u;
      }
    }
  } else {
    const int c0 = tc * 8 - 128;
    float bv[8];
#pragma unroll
    for (int c = 0; c < 8; ++c) bv[c] = bias2 ? bias2[c0 + c] : 0.f;
#pragma unroll
    for (int i = 0; i < 8; ++i) {
      const int row = row0 + trg * 8 + i;
      if (row < n) {
        float* yp = Yf + (size_t)row * 128 + c0;
        *(float4*)yp = make_float4(acc[i][0] + bv[0], acc[i][1] + bv[1],
                                   acc[i][2] + bv[2], acc[i][3] + bv[3]);
        *(float4*)(yp + 4) = make_float4(acc[i][4] + bv[4], acc[i][5] + bv[5],
                                         acc[i][6] + bv[6], acc[i][7] + bv[7]);
      }
    }
  }
}

// ---------- GEMM: Y[n,C] = X[n,128] @ W[128,C] (+bias), f32 in; Y f32 or bf16 ----------
template <int C, bool YBF>
__launch_bounds__(256)
__global__ void gemm_k128(const float* Xv, const float* __restrict__ Wf,
                          const float* __restrict__ biasf, void* Yv, int n) {
  constexpr int TC = C / 32;
  __shared__ float xs[64 * 32];
  __shared__ float wsm[32 * C];
  const int t = threadIdx.x;
  const int tc = t & 31;
  const int trg = t >> 5;
  const int row0 = blockIdx.x * 64;

  float acc[8][TC];
#pragma unroll
  for (int i = 0; i < 8; ++i)
#pragma unroll
    for (int c = 0; c < TC; ++c) acc[i][c] = 0.f;

  for (int kc = 0; kc < 128; kc += 32) {
    {
      const int r = t >> 2;
      const int j = (t & 3) * 8;
      const int row = row0 + r;
      float v[8];
      if (row < n) {
        const float* xp = Xv + (size_t)row * 128 + kc + j;
        float4 a = *(const float4*)xp;
        float4 b = *(const float4*)(xp + 4);
        v[0] = a.x; v[1] = a.y; v[2] = a.z; v[3] = a.w;
        v[4] = b.x; v[5] = b.y; v[6] = b.z; v[7] = b.w;
      } else {
#pragma unroll
        for (int q = 0; q < 8; ++q) v[q] = 0.f;
      }
      *(float4*)&xs[r * 32 + j]     = make_float4(v[0], v[1], v[2], v[3]);
      *(float4*)&xs[r * 32 + j + 4] = make_float4(v[4], v[5], v[6], v[7]);
    }
    {
      constexpr int per = (32 * C) / 256;
      const float* wp = Wf + (size_t)kc * C + t * per;
      float* wl = wsm + t * per;
#pragma unroll
      for (int q = 0; q < per; q += 4) *(float4*)(wl + q) = *(const float4*)(wp + q);
    }
    __syncthreads();
#pragma unroll
    for (int k = 0; k < 32; k += 4) {
      float wv[4][TC];
#pragma unroll
      for (int k2 = 0; k2 < 4; ++k2) {
        if constexpr (TC == 4) {
          float4 w4 = *(const float4*)&wsm[(k + k2) * C + tc * 4];
          wv[k2][0] = w4.x; wv[k2][1] = w4.y; wv[k2][2] = w4.z; wv[k2][3] = w4.w;
        } else {
          float2 w2 = *(const float2*)&wsm[(k + k2) * C + tc * 2];
          wv[k2][0] = w2.x; wv[k2][1] = w2.y;
        }
      }
#pragma unroll
      for (int i = 0; i < 8; ++i) {
        float4 x4 = *(const float4*)&xs[(trg * 8 + i) * 32 + k];
        float xa[4] = {x4.x, x4.y, x4.z, x4.w};
#pragma unroll
        for (int k2 = 0; k2 < 4; ++k2)
#pragma unroll
          for (int c = 0; c < TC; ++c)
            acc[i][c] = fmaf(xa[k2], wv[k2][c], acc[i][c]);
      }
    }
    __syncthreads();
  }
  float bv[TC];
#pragma unroll
  for (int c = 0; c < TC; ++c) bv[c] = biasf ? biasf[tc * TC + c] : 0.f;
#pragma unroll
  for (int i = 0; i < 8; ++i) {
    const int row = row0 + trg * 8 + i;
    if (row < n) {
      float r[TC];
#pragma unroll
      for (int c = 0; c < TC; ++c) r[c] = acc[i][c] + bv[c];
      if constexpr (YBF) {
        unsigned short* yp = (unsigned short*)Yv + (size_t)row * C + tc * TC;
        if constexpr (TC == 4) {
          uint2 u;
          u.x = (unsigned)f2bf(r[0]) | ((unsigned)f2bf(r[1]) << 16);
          u.y = (unsigned)f2bf(r[2]) | ((unsigned)f2bf(r[3]) << 16);
          *(uint2*)yp = u;
        } else {
          *(unsigned*)yp = (unsigned)f2bf(r[0]) | ((unsigned)f2bf(r[1]) << 16);
        }
      } else {
        float* yp = (float*)Yv + (size_t)row * C + tc * TC;
        if constexpr (TC == 4) *(float4*)yp = make_float4(r[0], r[1], r[2], r[3]);
        else                   *(float2*)yp = make_float2(r[0], r[1]);
      }
    }
  }
}

// ---------- per-node attention logits from bf16 hg (strided rows) ----------
template <int C>
__launch_bounds__(256)
__global__ void attn_logits2(const unsigned short* __restrict__ hg, int stride,
                             const float* __restrict__ asrc, const float* __restrict__ adst,
                             float* __restrict__ als, float* __restrict__ ald, int n) {
  const int node = blockIdx.x * 4 + (threadIdx.x >> 6);
  if (node >= n) return;
  const int lane = threadIdx.x & 63;
  float s, d;
  if constexpr (C == 128) {
    unsigned raw = *(const unsigned*)(hg + (size_t)node * stride + 2 * lane);
    float h0 = __uint_as_float(raw << 16);
    float h1 = __uint_as_float(raw & 0xFFFF0000u);
    float2 av = *(const float2*)(asrc + 2 * lane);
    float2 dv = *(const float2*)(adst + 2 * lane);
    s = h0 * av.x + h1 * av.y;
    d = h0 * dv.x + h1 * dv.y;
  } else {
    float h0 = bf2f(hg[(size_t)node * stride + lane]);
    s = h0 * asrc[lane];
    d = h0 * adst[lane];
  }
  for (int o = 32; o > 0; o >>= 1) {
    s += __shfl_xor(s, o, 64);
    d += __shfl_xor(d, o, 64);
  }
  if (lane == 0) { als[node] = s; ald[node] = d; }
}

// ---------- fused aggregation: one wave per node, lane-parallel softmax ----------
template <int C>
__launch_bounds__(256)
__global__ void gat_agg3(const unsigned short* __restrict__ hg, int stride,
                         const float* __restrict__ als, const float* __restrict__ aldv,
                         const int* __restrict__ rp, const int* __restrict__ col,
                         const float* __restrict__ biasf, float* __restrict__ outv,
                         const float* base, int n, int self_loop, int act) {
  const int node = blockIdx.x * 4 + (threadIdx.x >> 6);
  if (node >= n) return;
  const int lane = threadIdx.x & 63;
  const int beg = rp[node];
  const int deg = rp[node + 1] - beg;
  const int total = deg + self_loop;
  const float ad = aldv[node];

  float m = -INFINITY, den = 0.f, a0 = 0.f, a1 = 0.f;

  for (int cb = 0; cb < total; cb += 64) {
    const int idx = cb + lane;
    const bool valid = idx < total;
    int s = node;
    if (valid && idx < deg) s = col[beg + idx];
    float l = -INFINITY;
    if (valid) {
      float v = als[s] + ad;
      l = (v > 0.f) ? v : 0.2f * v;  // LeakyReLU(0.2)
    }
    float cm = l;
#pragma unroll
    for (int o = 32; o > 0; o >>= 1) cm = fmaxf(cm, __shfl_xor(cm, o, 64));
    const float newm = fmaxf(m, cm);
    const float scale = __expf(m - newm);
    den *= scale; a0 *= scale; a1 *= scale;
    m = newm;
    const float e = valid ? __expf(l - m) : 0.f;
    float cd = e;
#pragma unroll
    for (int o = 32; o > 0; o >>= 1) cd += __shfl_xor(cd, o, 64);
    den += cd;

    const int cnt = (total - cb < 64) ? (total - cb) : 64;
    int j = 0;
    for (; j + 4 <= cnt; j += 4) {
      float w0 = __shfl(e, j, 64),     w1 = __shfl(e, j + 1, 64);
      float w2 = __shfl(e, j + 2, 64), w3 = __shfl(e, j + 3, 64);
      int s0 = __shfl(s, j, 64),     s1 = __shfl(s, j + 1, 64);
      int s2 = __shfl(s, j + 2, 64), s3 = __shfl(s, j + 3, 64);
      if constexpr (C == 128) {
        unsigned r0 = *(const unsigned*)(hg + (size_t)s0 * stride + 2 * lane);
        unsigned r1 = *(const unsigned*)(hg + (size_t)s1 * stride + 2 * lane);
        unsigned r2 = *(const unsigned*)(hg + (size_t)s2 * stride + 2 * lane);
        unsigned r3 = *(const unsigned*)(hg + (size_t)s3 * stride + 2 * lane);
        a0 = fmaf(w0, __uint_as_float(r0 << 16), a0);
        a1 = fmaf(w0, __uint_as_float(r0 & 0xFFFF0000u), a1);
        a0 = fmaf(w1, __uint_as_float(r1 << 16), a0);
        a1 = fmaf(w1, __uint_as_float(r1 & 0xFFFF0000u), a1);
        a0 = fmaf(w2, __uint_as_float(r2 << 16), a0);
        a1 = fmaf(w2, __uint_as_float(r2 & 0xFFFF0000u), a1);
        a0 = fmaf(w3, __uint_as_float(r3 << 16), a0);
        a1 = fmaf(w3, __uint_as_float(r3 & 0xFFFF0000u), a1);
      } else {
        float h0 = bf2f(hg[(size_t)s0 * stride + lane]);
        float h1 = bf2f(hg[(size_t)s1 * stride + lane]);
        float h2 = bf2f(hg[(size_t)s2 * stride + lane]);
        float h3 = bf2f(hg[(size_t)s3 * stride + lane]);
        a0 = fmaf(w0, h0, a0); a0 = fmaf(w1, h1, a0);
        a0 = fmaf(w2, h2, a0); a0 = fmaf(w3, h3, a0);
      }
    }
    for (; j < cnt; ++j) {
      float wj = __shfl(e, j, 64);
      int sj = __shfl(s, j, 64);
      if constexpr (C == 128) {
        unsigned raw = *(const unsigned*)(hg + (size_t)sj * stride + 2 * lane);
        a0 = fmaf(wj, __uint_as_float(raw << 16), a0);
        a1 = fmaf(wj, __uint_as_float(raw & 0xFFFF0000u), a1);
      } else {
        a0 = fmaf(wj, bf2f(hg[(size_t)sj * stride + lane]), a0);
      }
    }
  }

  const float inv = 1.f / (den + 1e-16f);
  if constexpr (C == 128) {
    const size_t o = (size_t)node * 128 + 2 * lane;
    float2 bv = *(const float2*)(biasf + 2 * lane);
    float r0 = a0 * inv + bv.x;
    float r1 = a1 * inv + bv.y;
    if (base) { float2 bs = *(const float2*)(base + o); r0 += bs.x; r1 += bs.y; }
    if (act) {
      r0 = (r0 > 0.f) ? r0 : 0.01f * r0;
      r1 = (r1 > 0.f) ? r1 : 0.01f * r1;
    }
    *(float2*)(outv + o) = make_float2(r0, r1);
  } else {
    const size_t o = (size_t)node * 64 + lane;
    float r0 = a0 * inv + biasf[lane];
    if (base) r0 += base[o];
    if (act) r0 = (r0 > 0.f) ? r0 : 0.01f * r0;
    outv[o] = r0;
  }
}

extern "C" void kernel_launch(void* const* d_in, const int* in_sizes, int n_in,
                              void* d_out, int out_size, void* d_ws, size_t ws_size,
                              hipStream_t stream) {
  const int N = in_sizes[0] / 128;   // 100000
  const int E = in_sizes[1] / 2;     // 1600000
  const int W = (N + NB - 1) / NB;   // nodes per bucket (<=1024)

  const float* x    = (const float*)d_in[0];
  const int*   ei   = (const int*)d_in[1];
  const float* W0   = (const float*)d_in[2];
  const float* as0  = (const float*)d_in[3];
  const float* ad0  = (const float*)d_in[4];
  const float* b0   = (const float*)d_in[5];
  const float* slW0 = (const float*)d_in[6];
  const float* slb0 = (const float*)d_in[7];
  const float* W1   = (const float*)d_in[8];
  const float* as1  = (const float*)d_in[9];
  const float* ad1  = (const float*)d_in[10];
  const float* b1   = (const float*)d_in[11];
  const float* slW1 = (const float*)d_in[12];
  const float* slb1 = (const float*)d_in[13];
  const float* Wmu  = (const float*)d_in[14];
  const float* asmu = (const float*)d_in[15];
  const float* admu = (const float*)d_in[16];
  const float* bmu  = (const float*)d_in[17];
  const float* Wlv  = (const float*)d_in[18];
  const float* aslv = (const float*)d_in[19];
  const float* adlv = (const float*)d_in[20];
  const float* blv  = (const float*)d_in[21];

  float*          outF = (float*)d_out;
  unsigned short* hgB  = (unsigned short*)d_out;  // layers 0/1 hg lives in d_out

  auto al = [](size_t b) { return (b + 255) & ~(size_t)255; };
  const size_t szH0  = al((size_t)N * 128 * 4);
  const size_t szHgM = al((size_t)N * 128 * 2);
  const size_t szF   = al((size_t)N * 4);
  const size_t szRp  = al((size_t)(N + 1) * 4);
  const size_t szCol = al((size_t)E * 4);
  const size_t szWhl = al(128 * 128 * 4);
  const size_t szWd  = al(128 * 256 * 4);
  const size_t fixed = szH0 + 3 * szF + szRp + szCol + 2 * szWd + 2048 + 1024;
  const bool merged = fixed + szHgM + szWhl <= ws_size;

  char* w = (char*)d_ws;
  auto carve = [&](size_t bytes) -> char* { char* p = w; w += al(bytes); return p; };
  float*          h0   = (float*)carve((size_t)N * 128 * 4);
  unsigned short* hgHd = (unsigned short*)carve(merged ? (size_t)N * 128 * 2 : (size_t)N * 64 * 2);
  float*          als  = (float*)carve((size_t)N * 4);
  float*          ald  = (float*)carve((size_t)N * 4);
  int*            cnt  = (int*)carve((size_t)N * 4);
  int*            rp   = (int*)carve((size_t)(N + 1) * 4);
  int*            col  = (int*)carve((size_t)E * 4);
  int*            bsum = (int*)carve(512);
  int*            bhist= (int*)carve(NB * 4);
  int*            boffs= (int*)carve((NB + 1) * 4);
  int*            bcur = (int*)carve(NB * 4);
  int*            flag = (int*)carve(4);
  float*          Wd0  = (float*)carve(128 * 256 * 4);
  float*          Wd1  = (float*)carve(128 * 256 * 4);
  float*          Whl  = merged ? (float*)carve(128 * 128 * 4) : nullptr;
  int2*           ebuf = (int2*)h0;  // alias: h0 is dead during CSR build

  const int gE  = (E + 255) / 256;
  const int gB4 = (E + 4095) / 4096;
  const int gG  = (N + 63) / 64;
  const int gW  = (N + 3) / 4;
  const int nb  = (N + 1023) / 1024;

  // --- probe + CSR build (bucketed: no scatter write-amp) ---
  hipMemsetAsync(flag, 0, 4, stream);
  hipMemsetAsync(cnt, 0, (size_t)N * 4, stream);
  hipMemsetAsync(bhist, 0, NB * 4, stream);
  detect_kernel<<<1, 256, 0, stream>>>(ei, flag);
  hist_kernel<<<gE, 256, 0, stream>>>(ei, flag, cnt, E);
  bucket_hist<<<gB4, 256, 0, stream>>>(ei, flag, bhist, E, W);
  scan_block<<<nb, 256, 0, stream>>>(cnt, rp, bsum, N);
  scan_tops<<<1, 128, 0, stream>>>(bsum, rp, nb, N);
  scan_add<<<nb, 256, 0, stream>>>(rp, bsum, N);
  bucket_scan<<<1, NB, 0, stream>>>(bhist, boffs, bcur);
  bucket_scatter<<<gB4, 256, 0, stream>>>(ei, flag, bcur, ebuf, E, W);
  bucket_fill<<<NB, 256, 0, stream>>>(ebuf, boffs, rp, col, N, W);

  // --- weight packing (tiny) ---
  pack_dual<<<64, 256, 0, stream>>>(W0, slW0, Wd0);
  pack_dual<<<64, 256, 0, stream>>>(W1, slW1, Wd1);
  if (merged) pack_heads<<<32, 256, 0, stream>>>(Wmu, Wlv, Whl);

  // --- layer 0: dual GEMM + logits + fused agg ---
  gemm_dual<<<gG, 256, 0, stream>>>(x, Wd0, slb0, hgB, h0, N);
  attn_logits2<128><<<gW, 256, 0, stream>>>(hgB, 128, as0, ad0, als, ald, N);
  gat_agg3<128><<<gW, 256, 0, stream>>>(hgB, 128, als, ald, rp, col, b0, h0, h0, N, 0, 1);

  // --- layer 1 (self loops); h0 updated in place ---
  gemm_dual<<<gG, 256, 0, stream>>>(h0, Wd1, slb1, hgB, h0, N);
  attn_logits2<128><<<gW, 256, 0, stream>>>(hgB, 128, as1, ad1, als, ald, N);
  gat_agg3<128><<<gW, 256, 0, stream>>>(hgB, 128, als, ald, rp, col, b1, h0, h0, N, 1, 1);

  // --- heads ---
  if (merged) {
    gemm_k128<128, true><<<gG, 256, 0, stream>>>(h0, Whl, nullptr, hgHd, N);
    attn_logits2<64><<<gW, 256, 0, stream>>>(hgHd, 128, asmu, admu, als, ald, N);
    gat_agg3<64><<<gW, 256, 0, stream>>>(hgHd, 128, als, ald, rp, col, bmu,
                                         outF, nullptr, N, 1, 0);
    attn_logits2<64><<<gW, 256, 0, stream>>>(hgHd + 64, 128, aslv, adlv, als, ald, N);
    gat_agg3<64><<<gW, 256, 0, stream>>>(hgHd + 64, 128, als, ald, rp, col, blv,
                                         outF + (size_t)N * 64, nullptr, N, 1, 0);
  } else {
    gemm_k128<64, true><<<gG, 256, 0, stream>>>(h0, Wmu, nullptr, hgHd, N);
    attn_logits2<64><<<gW, 256, 0, stream>>>(hgHd, 64, asmu, admu, als, ald, N);
    gat_agg3<64><<<gW, 256, 0, stream>>>(hgHd, 64, als, ald, rp, col, bmu,
                                         outF, nullptr, N, 1, 0);
    gemm_k128<64, true><<<gG, 256, 0, stream>>>(h0, Wlv, nullptr, hgHd, N);
    attn_logits2<64><<<gW, 256, 0, stream>>>(hgHd, 64, aslv, adlv, als, ald, N);
    gat_agg3<64><<<gW, 256, 0, stream>>>(hgHd, 64, als, ald, rp, col, blv,
                                         outF + (size_t)N * 64, nullptr, N, 1, 0);
  }
}

// Round 7
// 687.575 us; speedup vs baseline: 2.2282x; 1.3181x over previous
//
#include <hip/hip_runtime.h>
#include <cstdint>
#include <cstddef>

// ---------- bf16 helpers (OCP bf16 = upper 16 bits of f32) ----------
__device__ __forceinline__ float bf2f(unsigned short u) {
  return __uint_as_float(((unsigned)u) << 16);
}
__device__ __forceinline__ unsigned short f2bf(float f) {
  unsigned u = __float_as_uint(f);
  u = (u + 0x7FFFu + ((u >> 16) & 1u)) >> 16;  // RNE
  return (unsigned short)u;
}

typedef __attribute__((ext_vector_type(8))) short bf16x8;
typedef __attribute__((ext_vector_type(4))) float f32x4;

// ---------- edge_index layout probe ----------
__global__ void detect_kernel(const int* __restrict__ ei, int* __restrict__ flag) {
  int any = 0;
  for (int j = threadIdx.x; j < 4096; j += 256) any |= (ei[2 * j + 1] != 0);
  if (any) atomicOr(flag, 1);  // 1 => int32 layout
}

__device__ __forceinline__ int edge_src(const int* ei, int f, int e, int i) {
  return f ? ei[i] : ei[2 * (size_t)i];
}
__device__ __forceinline__ int edge_dst(const int* ei, int f, int e, int i) {
  return f ? ei[(size_t)e + i] : ei[2 * (size_t)e + 2 * (size_t)i];
}

// ---------- per-node degree histogram ----------
__global__ void hist_kernel(const int* __restrict__ ei, const int* __restrict__ flag,
                            int* __restrict__ cnt, int e) {
  int i = blockIdx.x * blockDim.x + threadIdx.x;
  if (i < e) atomicAdd(&cnt[edge_dst(ei, *flag, e, i)], 1);
}

// two-level scan for rp
__global__ void scan_block(const int* __restrict__ cnt, int* __restrict__ rp,
                           int* __restrict__ bsum, int n) {
  __shared__ int lds[256];
  const int t = threadIdx.x;
  const int base = blockIdx.x * 1024 + t * 4;
  int v0 = (base     < n) ? cnt[base]     : 0;
  int v1 = (base + 1 < n) ? cnt[base + 1] : 0;
  int v2 = (base + 2 < n) ? cnt[base + 2] : 0;
  int v3 = (base + 3 < n) ? cnt[base + 3] : 0;
  int s = v0 + v1 + v2 + v3;
  lds[t] = s;
  __syncthreads();
  for (int off = 1; off < 256; off <<= 1) {
    int y = (t >= off) ? lds[t - off] : 0;
    __syncthreads();
    lds[t] += y;
    __syncthreads();
  }
  int excl = lds[t] - s;
  if (base     < n) rp[base]     = excl;
  if (base + 1 < n) rp[base + 1] = excl + v0;
  if (base + 2 < n) rp[base + 2] = excl + v0 + v1;
  if (base + 3 < n) rp[base + 3] = excl + v0 + v1 + v2;
  if (t == 255) bsum[blockIdx.x] = lds[255];
}

__global__ void scan_tops(int* __restrict__ bsum, int* __restrict__ rp, int nb, int n) {
  __shared__ int lds[128];
  const int t = threadIdx.x;
  int v = (t < nb) ? bsum[t] : 0;
  lds[t] = v;
  __syncthreads();
  for (int off = 1; off < 128; off <<= 1) {
    int y = (t >= off) ? lds[t - off] : 0;
    __syncthreads();
    lds[t] += y;
    __syncthreads();
  }
  if (t < nb) bsum[t] = lds[t] - v;
  if (t == 127) rp[n] = lds[127];
}

__global__ void scan_add(int* __restrict__ rp, const int* __restrict__ bsum, int n) {
  const int base = blockIdx.x * 1024 + threadIdx.x * 4;
  const int add = bsum[blockIdx.x];
#pragma unroll
  for (int i = 0; i < 4; ++i)
    if (base + i < n) rp[base + i] += add;
}

// ---------- bucketed CSR fill ----------
#define NB 128

__global__ void bucket_hist(const int* __restrict__ ei, const int* __restrict__ flag,
                            int* __restrict__ bhist, int e, int W) {
  __shared__ int lh[NB];
  const int t = threadIdx.x;
  if (t < NB) lh[t] = 0;
  __syncthreads();
  const int base = blockIdx.x * 4096;
  const int f = *flag;
  for (int j = t; j < 4096; j += 256) {
    int i = base + j;
    if (i < e) atomicAdd(&lh[edge_dst(ei, f, e, i) / W], 1);
  }
  __syncthreads();
  if (t < NB && lh[t]) atomicAdd(&bhist[t], lh[t]);
}

__global__ void bucket_scan(const int* __restrict__ bhist, int* __restrict__ boffs,
                            int* __restrict__ bcur) {
  __shared__ int lds[NB];
  const int t = threadIdx.x;
  int v = bhist[t];
  lds[t] = v;
  __syncthreads();
  for (int off = 1; off < NB; off <<= 1) {
    int y = (t >= off) ? lds[t - off] : 0;
    __syncthreads();
    lds[t] += y;
    __syncthreads();
  }
  int excl = lds[t] - v;
  boffs[t] = excl;
  bcur[t] = excl;
  if (t == NB - 1) boffs[NB] = lds[NB - 1];
}

__global__ void bucket_scatter(const int* __restrict__ ei, const int* __restrict__ flag,
                               int* __restrict__ bcur, int2* __restrict__ ebuf,
                               int e, int W) {
  __shared__ int lh[NB];
  __shared__ int lbase[NB];
  const int t = threadIdx.x;
  if (t < NB) lh[t] = 0;
  __syncthreads();
  const int base = blockIdx.x * 4096;
  const int f = *flag;
  for (int j = t; j < 4096; j += 256) {
    int i = base + j;
    if (i < e) atomicAdd(&lh[edge_dst(ei, f, e, i) / W], 1);
  }
  __syncthreads();
  if (t < NB) {
    lbase[t] = lh[t] ? atomicAdd(&bcur[t], lh[t]) : 0;
    lh[t] = 0;
  }
  __syncthreads();
  for (int j = t; j < 4096; j += 256) {
    int i = base + j;
    if (i < e) {
      int d = edge_dst(ei, f, e, i);
      int s = edge_src(ei, f, e, i);
      int b = d / W;
      int off = atomicAdd(&lh[b], 1);
      ebuf[lbase[b] + off] = make_int2(s, d);
    }
  }
}

__global__ void bucket_fill(const int2* __restrict__ ebuf, const int* __restrict__ boffs,
                            const int* __restrict__ rp, int* __restrict__ col,
                            int n, int W) {
  __shared__ int cur[1024];
  const int b = blockIdx.x;
  const int lo = b * W;
  const int nn = min(W, n - lo);
  if (nn <= 0) return;
  for (int i = threadIdx.x; i < nn; i += 256) cur[i] = rp[lo + i];
  __syncthreads();
  const int beg = boffs[b], end = boffs[b + 1];
  for (int p = beg + threadIdx.x; p < end; p += 256) {
    int2 sd = ebuf[p];
    int pos = atomicAdd(&cur[sd.y - lo], 1);
    col[pos] = sd.x;
  }
}

// ---------- pack W[128][128] f32 into MFMA B-fragment order (bf16) ----------
// Wpk[((ks*8+nt)*64+lane)*8 + j] = bf16(W[ks*32 + (lane>>4)*8 + j][nt*16 + (lane&15)])
__global__ void pack_mfma_b(const float* __restrict__ Wf, unsigned short* __restrict__ Wpk) {
  int i = blockIdx.x * 256 + threadIdx.x;  // 2048
  if (i >= 2048) return;
  int lane = i & 63, nt = (i >> 6) & 7, ks = i >> 9;
  int nn = lane & 15, q = lane >> 4;
  int k0 = ks * 32 + q * 8, col = nt * 16 + nn;
  unsigned short o[8];
#pragma unroll
  for (int j = 0; j < 8; ++j) o[j] = f2bf(Wf[(size_t)(k0 + j) * 128 + col]);
  uint4 u;
  u.x = (unsigned)o[0] | ((unsigned)o[1] << 16);
  u.y = (unsigned)o[2] | ((unsigned)o[3] << 16);
  u.z = (unsigned)o[4] | ((unsigned)o[5] << 16);
  u.w = (unsigned)o[6] | ((unsigned)o[7] << 16);
  *(uint4*)(Wpk + (size_t)i * 8) = u;
}

// heads: merged [Wmu | Wlv], each [128][64] f32
__global__ void pack_mfma_head(const float* __restrict__ Wmu, const float* __restrict__ Wlv,
                               unsigned short* __restrict__ Wpk) {
  int i = blockIdx.x * 256 + threadIdx.x;  // 2048
  if (i >= 2048) return;
  int lane = i & 63, nt = (i >> 6) & 7, ks = i >> 9;
  int nn = lane & 15, q = lane >> 4;
  int k0 = ks * 32 + q * 8, col = nt * 16 + nn;
  unsigned short o[8];
#pragma unroll
  for (int j = 0; j < 8; ++j) {
    float v = (col < 64) ? Wmu[(size_t)(k0 + j) * 64 + col]
                         : Wlv[(size_t)(k0 + j) * 64 + (col - 64)];
    o[j] = f2bf(v);
  }
  uint4 u;
  u.x = (unsigned)o[0] | ((unsigned)o[1] << 16);
  u.y = (unsigned)o[2] | ((unsigned)o[3] << 16);
  u.z = (unsigned)o[4] | ((unsigned)o[5] << 16);
  u.w = (unsigned)o[6] | ((unsigned)o[7] << 16);
  *(uint4*)(Wpk + (size_t)i * 8) = u;
}

// ---------- MFMA GEMM: hg[n][128](bf16) = X[n][128](f32) @ W ; logits in epilogue ----------
// No LDS, no syncthreads. Wave w: rows blockIdx*64 + w*16 .. +15, all 128 cols.
// HEAD=false: als/ald scalar (dot with a0s/a0d over all 128 cols).
// HEAD=true : als/ald are float2 arrays; mu logits from cols 0..63 (a0*), lv from 64..127 (a1*).
template <bool HEAD>
__launch_bounds__(256)
__global__ void gemm_mfma(const float* __restrict__ X, const unsigned short* __restrict__ Wpk,
                          const float* __restrict__ a0s, const float* __restrict__ a0d,
                          const float* __restrict__ a1s, const float* __restrict__ a1d,
                          unsigned short* __restrict__ hg,
                          float* __restrict__ als, float* __restrict__ ald, int n) {
  const int wave = threadIdx.x >> 6;
  const int lane = threadIdx.x & 63;
  const int nidx = lane & 15, q = lane >> 4;
  const int r0 = blockIdx.x * 64 + wave * 16;
  const int arow = r0 + nidx;

  f32x4 acc[8];
#pragma unroll
  for (int nt = 0; nt < 8; ++nt) acc[nt] = (f32x4){0.f, 0.f, 0.f, 0.f};

#pragma unroll
  for (int ks = 0; ks < 4; ++ks) {
    union { unsigned short u[8]; bf16x8 v; } af;
    if (arow < n) {
      const float* xp = X + (size_t)arow * 128 + ks * 32 + q * 8;
      float4 a = *(const float4*)xp;
      float4 b = *(const float4*)(xp + 4);
      af.u[0] = f2bf(a.x); af.u[1] = f2bf(a.y); af.u[2] = f2bf(a.z); af.u[3] = f2bf(a.w);
      af.u[4] = f2bf(b.x); af.u[5] = f2bf(b.y); af.u[6] = f2bf(b.z); af.u[7] = f2bf(b.w);
    } else {
#pragma unroll
      for (int j = 0; j < 8; ++j) af.u[j] = 0;
    }
    const unsigned short* bp = Wpk + ((size_t)ks * 8 * 64 + lane) * 8;
#pragma unroll
    for (int nt = 0; nt < 8; ++nt) {
      bf16x8 bfm = *(const bf16x8*)(bp + (size_t)nt * 64 * 8);
      acc[nt] = __builtin_amdgcn_mfma_f32_16x16x32_bf16(af.v, bfm, acc[nt], 0, 0, 0);
    }
  }

  // epilogue: round to bf16, store hg, compute logits from rounded values
  float dv[8][4];
#pragma unroll
  for (int nt = 0; nt < 8; ++nt) {
#pragma unroll
    for (int r = 0; r < 4; ++r) {
      unsigned short rb = f2bf(acc[nt][r]);
      dv[nt][r] = bf2f(rb);
      int row = r0 + q * 4 + r;
      if (row < n) hg[(size_t)row * 128 + nt * 16 + nidx] = rb;
    }
  }

  if constexpr (!HEAD) {
    float ps[4] = {0, 0, 0, 0}, pd[4] = {0, 0, 0, 0};
#pragma unroll
    for (int nt = 0; nt < 8; ++nt) {
      float as_ = a0s[nt * 16 + nidx];
      float ad_ = a0d[nt * 16 + nidx];
#pragma unroll
      for (int r = 0; r < 4; ++r) {
        ps[r] = fmaf(dv[nt][r], as_, ps[r]);
        pd[r] = fmaf(dv[nt][r], ad_, pd[r]);
      }
    }
#pragma unroll
    for (int r = 0; r < 4; ++r) {
#pragma unroll
      for (int o = 8; o > 0; o >>= 1) {
        ps[r] += __shfl_xor(ps[r], o, 64);
        pd[r] += __shfl_xor(pd[r], o, 64);
      }
      int row = r0 + q * 4 + r;
      if (nidx == 0 && row < n) { als[row] = ps[r]; ald[row] = pd[r]; }
    }
  } else {
    float pms[4] = {0, 0, 0, 0}, pmd[4] = {0, 0, 0, 0};
    float pls[4] = {0, 0, 0, 0}, pld[4] = {0, 0, 0, 0};
#pragma unroll
    for (int nt = 0; nt < 4; ++nt) {
      float as_ = a0s[nt * 16 + nidx];
      float ad_ = a0d[nt * 16 + nidx];
#pragma unroll
      for (int r = 0; r < 4; ++r) {
        pms[r] = fmaf(dv[nt][r], as_, pms[r]);
        pmd[r] = fmaf(dv[nt][r], ad_, pmd[r]);
      }
    }
#pragma unroll
    for (int nt = 4; nt < 8; ++nt) {
      float as_ = a1s[(nt - 4) * 16 + nidx];
      float ad_ = a1d[(nt - 4) * 16 + nidx];
#pragma unroll
      for (int r = 0; r < 4; ++r) {
        pls[r] = fmaf(dv[nt][r], as_, pls[r]);
        pld[r] = fmaf(dv[nt][r], ad_, pld[r]);
      }
    }
#pragma unroll
    for (int r = 0; r < 4; ++r) {
#pragma unroll
      for (int o = 8; o > 0; o >>= 1) {
        pms[r] += __shfl_xor(pms[r], o, 64);
        pmd[r] += __shfl_xor(pmd[r], o, 64);
        pls[r] += __shfl_xor(pls[r], o, 64);
        pld[r] += __shfl_xor(pld[r], o, 64);
      }
      int row = r0 + q * 4 + r;
      if (nidx == 0 && row < n) {
        ((float2*)als)[row] = make_float2(pms[r], pls[r]);
        ((float2*)ald)[row] = make_float2(pmd[r], pld[r]);
      }
    }
  }
}

// ---------- f32 VALU GEMM (self-linear path): Y[n,128] = X[n,128]@W + bias ----------
template <int C, bool YBF>
__launch_bounds__(256)
__global__ void gemm_k128(const float* Xv, const float* __restrict__ Wf,
                          const float* __restrict__ biasf, void* Yv, int n) {
  constexpr int TC = C / 32;
  __shared__ float xs[64 * 32];
  __shared__ float wsm[32 * C];
  const int t = threadIdx.x;
  const int tc = t & 31;
  const int trg = t >> 5;
  const int row0 = blockIdx.x * 64;

  float acc[8][TC];
#pragma unroll
  for (int i = 0; i < 8; ++i)
#pragma unroll
    for (int c = 0; c < TC; ++c) acc[i][c] = 0.f;

  for (int kc = 0; kc < 128; kc += 32) {
    {
      const int r = t >> 2;
      const int j = (t & 3) * 8;
      const int row = row0 + r;
      float v[8];
      if (row < n) {
        const float* xp = Xv + (size_t)row * 128 + kc + j;
        float4 a = *(const float4*)xp;
        float4 b = *(const float4*)(xp + 4);
        v[0] = a.x; v[1] = a.y; v[2] = a.z; v[3] = a.w;
        v[4] = b.x; v[5] = b.y; v[6] = b.z; v[7] = b.w;
      } else {
#pragma unroll
        for (int q = 0; q < 8; ++q) v[q] = 0.f;
      }
      *(float4*)&xs[r * 32 + j]     = make_float4(v[0], v[1], v[2], v[3]);
      *(float4*)&xs[r * 32 + j + 4] = make_float4(v[4], v[5], v[6], v[7]);
    }
    {
      constexpr int per = (32 * C) / 256;
      const float* wp = Wf + (size_t)kc * C + t * per;
      float* wl = wsm + t * per;
#pragma unroll
      for (int q = 0; q < per; q += 4) *(float4*)(wl + q) = *(const float4*)(wp + q);
    }
    __syncthreads();
#pragma unroll
    for (int k = 0; k < 32; k += 4) {
      float wv[4][TC];
#pragma unroll
      for (int k2 = 0; k2 < 4; ++k2) {
        if constexpr (TC == 4) {
          float4 w4 = *(const float4*)&wsm[(k + k2) * C + tc * 4];
          wv[k2][0] = w4.x; wv[k2][1] = w4.y; wv[k2][2] = w4.z; wv[k2][3] = w4.w;
        } else {
          float2 w2 = *(const float2*)&wsm[(k + k2) * C + tc * 2];
          wv[k2][0] = w2.x; wv[k2][1] = w2.y;
        }
      }
#pragma unroll
      for (int i = 0; i < 8; ++i) {
        float4 x4 = *(const float4*)&xs[(trg * 8 + i) * 32 + k];
        float xa[4] = {x4.x, x4.y, x4.z, x4.w};
#pragma unroll
        for (int k2 = 0; k2 < 4; ++k2)
#pragma unroll
          for (int c = 0; c < TC; ++c)
            acc[i][c] = fmaf(xa[k2], wv[k2][c], acc[i][c]);
      }
    }
    __syncthreads();
  }
  float bv[TC];
#pragma unroll
  for (int c = 0; c < TC; ++c) bv[c] = biasf ? biasf[tc * TC + c] : 0.f;
#pragma unroll
  for (int i = 0; i < 8; ++i) {
    const int row = row0 + trg * 8 + i;
    if (row < n) {
      float r[TC];
#pragma unroll
      for (int c = 0; c < TC; ++c) r[c] = acc[i][c] + bv[c];
      if constexpr (YBF) {
        unsigned short* yp = (unsigned short*)Yv + (size_t)row * C + tc * TC;
        if constexpr (TC == 4) {
          uint2 u;
          u.x = (unsigned)f2bf(r[0]) | ((unsigned)f2bf(r[1]) << 16);
          u.y = (unsigned)f2bf(r[2]) | ((unsigned)f2bf(r[3]) << 16);
          *(uint2*)yp = u;
        } else {
          *(unsigned*)yp = (unsigned)f2bf(r[0]) | ((unsigned)f2bf(r[1]) << 16);
        }
      } else {
        float* yp = (float*)Yv + (size_t)row * C + tc * TC;
        if constexpr (TC == 4) *(float4*)yp = make_float4(r[0], r[1], r[2], r[3]);
        else                   *(float2*)yp = make_float2(r[0], r[1]);
      }
    }
  }
}

// ---------- layer aggregation: one wave per node, lane-parallel softmax, ILP-8 ----------
__launch_bounds__(256)
__global__ void gat_agg3(const unsigned short* __restrict__ hg,
                         const float* __restrict__ als, const float* __restrict__ aldv,
                         const int* __restrict__ rp, const int* __restrict__ col,
                         const float* __restrict__ biasf, float* __restrict__ outv,
                         const float* base, int n, int self_loop, int act) {
  const int node = blockIdx.x * 4 + (threadIdx.x >> 6);
  if (node >= n) return;
  const int lane = threadIdx.x & 63;
  const int beg = rp[node];
  const int deg = rp[node + 1] - beg;
  const int total = deg + self_loop;
  const float ad = aldv[node];

  float m = -INFINITY, den = 0.f, a0 = 0.f, a1 = 0.f;

  for (int cb = 0; cb < total; cb += 64) {
    const int idx = cb + lane;
    const bool valid = idx < total;
    int s = node;
    if (valid && idx < deg) s = col[beg + idx];
    float l = -INFINITY;
    if (valid) {
      float v = als[s] + ad;
      l = (v > 0.f) ? v : 0.2f * v;  // LeakyReLU(0.2)
    }
    float cm = l;
#pragma unroll
    for (int o = 32; o > 0; o >>= 1) cm = fmaxf(cm, __shfl_xor(cm, o, 64));
    const float newm = fmaxf(m, cm);
    const float scale = __expf(m - newm);
    den *= scale; a0 *= scale; a1 *= scale;
    m = newm;
    const float e = valid ? __expf(l - m) : 0.f;
    float cd = e;
#pragma unroll
    for (int o = 32; o > 0; o >>= 1) cd += __shfl_xor(cd, o, 64);
    den += cd;

    const int cnt = (total - cb < 64) ? (total - cb) : 64;
    int j = 0;
    for (; j + 8 <= cnt; j += 8) {
      float w[8]; int ss[8]; unsigned rr[8];
#pragma unroll
      for (int u = 0; u < 8; ++u) { w[u] = __shfl(e, j + u, 64); ss[u] = __shfl(s, j + u, 64); }
#pragma unroll
      for (int u = 0; u < 8; ++u) rr[u] = *(const unsigned*)(hg + (size_t)ss[u] * 128 + 2 * lane);
#pragma unroll
      for (int u = 0; u < 8; ++u) {
        a0 = fmaf(w[u], __uint_as_float(rr[u] << 16), a0);
        a1 = fmaf(w[u], __uint_as_float(rr[u] & 0xFFFF0000u), a1);
      }
    }
    for (; j + 4 <= cnt; j += 4) {
      float w[4]; int ss[4]; unsigned rr[4];
#pragma unroll
      for (int u = 0; u < 4; ++u) { w[u] = __shfl(e, j + u, 64); ss[u] = __shfl(s, j + u, 64); }
#pragma unroll
      for (int u = 0; u < 4; ++u) rr[u] = *(const unsigned*)(hg + (size_t)ss[u] * 128 + 2 * lane);
#pragma unroll
      for (int u = 0; u < 4; ++u) {
        a0 = fmaf(w[u], __uint_as_float(rr[u] << 16), a0);
        a1 = fmaf(w[u], __uint_as_float(rr[u] & 0xFFFF0000u), a1);
      }
    }
    for (; j < cnt; ++j) {
      float wj = __shfl(e, j, 64);
      int sj = __shfl(s, j, 64);
      unsigned raw = *(const unsigned*)(hg + (size_t)sj * 128 + 2 * lane);
      a0 = fmaf(wj, __uint_as_float(raw << 16), a0);
      a1 = fmaf(wj, __uint_as_float(raw & 0xFFFF0000u), a1);
    }
  }

  const float inv = 1.f / (den + 1e-16f);
  const size_t o = (size_t)node * 128 + 2 * lane;
  float2 bv = *(const float2*)(biasf + 2 * lane);
  float r0 = a0 * inv + bv.x;
  float r1 = a1 * inv + bv.y;
  if (base) { float2 bs = *(const float2*)(base + o); r0 += bs.x; r1 += bs.y; }
  if (act) {
    r0 = (r0 > 0.f) ? r0 : 0.01f * r0;
    r1 = (r1 > 0.f) ? r1 : 0.01f * r1;
  }
  *(float2*)(outv + o) = make_float2(r0, r1);
}

// ---------- dual-head aggregation: mu + logvar in ONE gather pass ----------
// hg rows are [mu(64) | lv(64)] bf16. Lanes 0..31 accumulate mu cols, 32..63 lv cols.
__launch_bounds__(256)
__global__ void gat_agg_dual(const unsigned short* __restrict__ hg,
                             const float2* __restrict__ alsH, const float2* __restrict__ aldH,
                             const int* __restrict__ rp, const int* __restrict__ col,
                             const float* __restrict__ bmu, const float* __restrict__ blv,
                             float* __restrict__ outF, int n) {
  const int node = blockIdx.x * 4 + (threadIdx.x >> 6);
  if (node >= n) return;
  const int lane = threadIdx.x & 63;
  const bool isMu = lane < 32;
  const int beg = rp[node];
  const int deg = rp[node + 1] - beg;
  const int total = deg + 1;  // heads always have self loop
  const float2 ad = aldH[node];

  float mM = -INFINITY, mL = -INFINITY, dM = 0.f, dL = 0.f;
  float a0 = 0.f, a1 = 0.f;

  for (int cb = 0; cb < total; cb += 64) {
    const int idx = cb + lane;
    const bool valid = idx < total;
    int s = node;
    if (valid && idx < deg) s = col[beg + idx];
    float lm = -INFINITY, ll = -INFINITY;
    if (valid) {
      float2 as_ = alsH[s];
      float vm = as_.x + ad.x; lm = (vm > 0.f) ? vm : 0.2f * vm;
      float vl = as_.y + ad.y; ll = (vl > 0.f) ? vl : 0.2f * vl;
    }
    float cm = lm, cl = ll;
#pragma unroll
    for (int o = 32; o > 0; o >>= 1) {
      cm = fmaxf(cm, __shfl_xor(cm, o, 64));
      cl = fmaxf(cl, __shfl_xor(cl, o, 64));
    }
    const float nM = fmaxf(mM, cm), nL = fmaxf(mL, cl);
    const float sM = __expf(mM - nM), sL = __expf(mL - nL);
    dM *= sM; dL *= sL;
    const float sc = isMu ? sM : sL;
    a0 *= sc; a1 *= sc;
    mM = nM; mL = nL;
    const float eM = valid ? __expf(lm - mM) : 0.f;
    const float eL = valid ? __expf(ll - mL) : 0.f;
    float cdM = eM, cdL = eL;
#pragma unroll
    for (int o = 32; o > 0; o >>= 1) {
      cdM += __shfl_xor(cdM, o, 64);
      cdL += __shfl_xor(cdL, o, 64);
    }
    dM += cdM; dL += cdL;

    const int cnt = (total - cb < 64) ? (total - cb) : 64;
    int j = 0;
    for (; j + 4 <= cnt; j += 4) {
      float w[4]; int ss[4]; unsigned rr[4];
#pragma unroll
      for (int u = 0; u < 4; ++u) {
        float wm = __shfl(eM, j + u, 64), wl = __shfl(eL, j + u, 64);
        w[u] = isMu ? wm : wl;
        ss[u] = __shfl(s, j + u, 64);
      }
#pragma unroll
      for (int u = 0; u < 4; ++u) rr[u] = *(const unsigned*)(hg + (size_t)ss[u] * 128 + 2 * lane);
#pragma unroll
      for (int u = 0; u < 4; ++u) {
        a0 = fmaf(w[u], __uint_as_float(rr[u] << 16), a0);
        a1 = fmaf(w[u], __uint_as_float(rr[u] & 0xFFFF0000u), a1);
      }
    }
    for (; j < cnt; ++j) {
      float wm = __shfl(eM, j, 64), wl = __shfl(eL, j, 64);
      float wj = isMu ? wm : wl;
      int sj = __shfl(s, j, 64);
      unsigned raw = *(const unsigned*)(hg + (size_t)sj * 128 + 2 * lane);
      a0 = fmaf(wj, __uint_as_float(raw << 16), a0);
      a1 = fmaf(wj, __uint_as_float(raw & 0xFFFF0000u), a1);
    }
  }

  const float inv = 1.f / ((isMu ? dM : dL) + 1e-16f);
  const int c = isMu ? 2 * lane : 2 * (lane - 32);
  const float* bb = isMu ? bmu : blv;
  float r0 = a0 * inv + bb[c];
  float r1 = a1 * inv + bb[c + 1];
  float* op = outF + (isMu ? 0 : (size_t)n * 64) + (size_t)node * 64 + c;
  *(float2*)op = make_float2(r0, r1);
}

extern "C" void kernel_launch(void* const* d_in, const int* in_sizes, int n_in,
                              void* d_out, int out_size, void* d_ws, size_t ws_size,
                              hipStream_t stream) {
  const int N = in_sizes[0] / 128;   // 100000
  const int E = in_sizes[1] / 2;     // 1600000
  const int W = (N + NB - 1) / NB;   // nodes per bucket (<=1024)

  const float* x    = (const float*)d_in[0];
  const int*   ei   = (const int*)d_in[1];
  const float* W0   = (const float*)d_in[2];
  const float* as0  = (const float*)d_in[3];
  const float* ad0  = (const float*)d_in[4];
  const float* b0   = (const float*)d_in[5];
  const float* slW0 = (const float*)d_in[6];
  const float* slb0 = (const float*)d_in[7];
  const float* W1   = (const float*)d_in[8];
  const float* as1  = (const float*)d_in[9];
  const float* ad1  = (const float*)d_in[10];
  const float* b1   = (const float*)d_in[11];
  const float* slW1 = (const float*)d_in[12];
  const float* slb1 = (const float*)d_in[13];
  const float* Wmu  = (const float*)d_in[14];
  const float* asmu = (const float*)d_in[15];
  const float* admu = (const float*)d_in[16];
  const float* bmu  = (const float*)d_in[17];
  const float* Wlv  = (const float*)d_in[18];
  const float* aslv = (const float*)d_in[19];
  const float* adlv = (const float*)d_in[20];
  const float* blv  = (const float*)d_in[21];

  float*          outF = (float*)d_out;
  unsigned short* hgB  = (unsigned short*)d_out;  // layers' hg lives in d_out (dead before heads write)

  char* w = (char*)d_ws;
  auto carve = [&](size_t bytes) -> char* {
    char* p = w;
    w += (bytes + 255) & ~(size_t)255;
    return p;
  };
  float*          h0    = (float*)carve((size_t)N * 128 * 4);           // 51.2 MB
  unsigned short* hgHd  = (unsigned short*)carve((size_t)N * 128 * 2);  // 25.6 MB
  float*          als   = (float*)carve((size_t)N * 4);
  float*          ald   = (float*)carve((size_t)N * 4);
  float2*         alsH  = (float2*)carve((size_t)N * 8);
  float2*         aldH  = (float2*)carve((size_t)N * 8);
  int*            cnt   = (int*)carve((size_t)N * 4);
  int*            rp    = (int*)carve((size_t)(N + 1) * 4);
  int*            col   = (int*)carve((size_t)E * 4);
  int*            bsum  = (int*)carve(512);
  int*            bhist = (int*)carve(NB * 4);
  int*            boffs = (int*)carve((NB + 1) * 4);
  int*            bcur  = (int*)carve(NB * 4);
  int*            flag  = (int*)carve(4);
  unsigned short* Wpk0  = (unsigned short*)carve(2048 * 8 * 2);
  unsigned short* Wpk1  = (unsigned short*)carve(2048 * 8 * 2);
  unsigned short* Wpkh  = (unsigned short*)carve(2048 * 8 * 2);
  int2*           ebuf  = (int2*)h0;  // alias: h0 dead during CSR build

  const int gE  = (E + 255) / 256;
  const int gB4 = (E + 4095) / 4096;
  const int gG  = (N + 63) / 64;
  const int gW  = (N + 3) / 4;
  const int nb  = (N + 1023) / 1024;

  // --- probe + bucketed CSR build ---
  hipMemsetAsync(flag, 0, 4, stream);
  hipMemsetAsync(cnt, 0, (size_t)N * 4, stream);
  hipMemsetAsync(bhist, 0, NB * 4, stream);
  detect_kernel<<<1, 256, 0, stream>>>(ei, flag);
  hist_kernel<<<gE, 256, 0, stream>>>(ei, flag, cnt, E);
  bucket_hist<<<gB4, 256, 0, stream>>>(ei, flag, bhist, E, W);
  scan_block<<<nb, 256, 0, stream>>>(cnt, rp, bsum, N);
  scan_tops<<<1, 128, 0, stream>>>(bsum, rp, nb, N);
  scan_add<<<nb, 256, 0, stream>>>(rp, bsum, N);
  bucket_scan<<<1, NB, 0, stream>>>(bhist, boffs, bcur);
  bucket_scatter<<<gB4, 256, 0, stream>>>(ei, flag, bcur, ebuf, E, W);
  bucket_fill<<<NB, 256, 0, stream>>>(ebuf, boffs, rp, col, N, W);

  // --- pack weights into MFMA B-fragment order (bf16) ---
  pack_mfma_b<<<8, 256, 0, stream>>>(W0, Wpk0);
  pack_mfma_b<<<8, 256, 0, stream>>>(W1, Wpk1);
  pack_mfma_head<<<8, 256, 0, stream>>>(Wmu, Wlv, Wpkh);

  // --- layer 0: MFMA hg-GEMM (+logits) ; f32 self-linear ; fused agg ---
  gemm_mfma<false><<<gG, 256, 0, stream>>>(x, Wpk0, as0, ad0, nullptr, nullptr,
                                           hgB, als, ald, N);
  gemm_k128<128, false><<<gG, 256, 0, stream>>>(x, slW0, slb0, h0, N);
  gat_agg3<<<gW, 256, 0, stream>>>(hgB, als, ald, rp, col, b0, h0, h0, N, 0, 1);

  // --- layer 1 (self loops); h0 updated in place after MFMA reads it ---
  gemm_mfma<false><<<gG, 256, 0, stream>>>(h0, Wpk1, as1, ad1, nullptr, nullptr,
                                           hgB, als, ald, N);
  gemm_k128<128, false><<<gG, 256, 0, stream>>>(h0, slW1, slb1, h0, N);
  gat_agg3<<<gW, 256, 0, stream>>>(hgB, als, ald, rp, col, b1, h0, h0, N, 1, 1);

  // --- heads: one merged MFMA GEMM (+both logit pairs), one dual gather pass ---
  gemm_mfma<true><<<gG, 256, 0, stream>>>(h0, Wpkh, asmu, admu, aslv, adlv,
                                          hgHd, (float*)alsH, (float*)aldH, N);
  gat_agg_dual<<<gW, 256, 0, stream>>>(hgHd, alsH, aldH, rp, col, bmu, blv, outF, N);
}